// Round 17
// baseline (213.557 us; speedup 1.0000x reference)
//
#include <hip/hip_runtime.h>
#include <math.h>

// ---------------------------------------------------------------------------
// GAT 2-layer forward (N=50000, F_in=256, H1=8, C1=32, C2=32, E=500000).
// R16: (1) gemm1 -> BN=256 single-pass (x fp32 read ONCE, was twice; B-tile
// w1t re-reads are L2-hit); wave tile 64x128 (acc 4x8). (2) alpha1 fused into
// gemm1 epilogue (per-head dot from acc registers + shfl_xor col-reduce) and
// alpha2 fused into gemm2 epilogue — removes 2 dispatches + 32 MB of h1b/h2
// re-reads. agg1f/agg2f and CSR chain frozen from R15.
// ---------------------------------------------------------------------------

typedef __attribute__((ext_vector_type(8))) short bf16x8;
typedef __attribute__((ext_vector_type(4))) float f32x4;

__device__ __forceinline__ float bf2f(ushort u) {
    union { uint i; float f; } v; v.i = ((uint)u) << 16; return v.f;
}
__device__ __forceinline__ ushort f2bf(float f) {  // round-to-nearest-even
    union { float f; uint i; } v; v.f = f;
    uint r = v.i + 0x7FFFu + ((v.i >> 16) & 1u);
    return (ushort)(r >> 16);
}
__device__ __forceinline__ uint pack2(float a, float b) {
    return (uint)f2bf(a) | ((uint)f2bf(b) << 16);
}

// int64 little-endian values < 2^31 => every odd 32-bit word is 0.
__global__ void detect_kernel(const int* ei32, int* flag) {
    __shared__ int cnt;
    if (threadIdx.x == 0) cnt = 0;
    __syncthreads();
    int nz = 0;
    for (int i = threadIdx.x; i < 1024; i += blockDim.x)
        if (ei32[2 * i + 1] != 0) nz++;
    atomicAdd(&cnt, nz);
    __syncthreads();
    if (threadIdx.x == 0) *flag = (cnt > 16) ? 1 : 0;  // 1 => int32 layout
}

__global__ void decode_degree_kernel(const void* ei, int E, int ET, int N,
                                     const int* __restrict__ flag,
                                     int* __restrict__ src, int* __restrict__ dst,
                                     int* __restrict__ deg) {
    int k = blockIdx.x * blockDim.x + threadIdx.x;
    if (k >= ET) return;
    int s, d;
    if (k < E) {
        if (*flag) {
            const int* p = (const int*)ei;
            s = p[k]; d = p[E + k];
        } else {
            const long long* p = (const long long*)ei;
            s = (int)p[k]; d = (int)p[E + k];
        }
    } else {
        s = d = k - E;  // self-loops appended
    }
    s = min(max(s, 0), N - 1);
    d = min(max(d, 0), N - 1);
    src[k] = s; dst[k] = d;
    atomicAdd(&deg[d], 1);
}

// --- 3-phase hierarchical exclusive scan (coalesced, parallel) -------------
__global__ __launch_bounds__(256) void scanA_kernel(const int* __restrict__ deg,
                                                    int* __restrict__ bsum, int n) {
    int i = blockIdx.x * 256 + threadIdx.x;
    int v = (i < n) ? deg[i] : 0;
#pragma unroll
    for (int s = 1; s < 64; s <<= 1) v += __shfl_xor(v, s, 64);
    __shared__ int ws[4];
    int lane = threadIdx.x & 63, wid = threadIdx.x >> 6;
    if (lane == 0) ws[wid] = v;
    __syncthreads();
    if (threadIdx.x == 0) bsum[blockIdx.x] = ws[0] + ws[1] + ws[2] + ws[3];
}

__global__ __launch_bounds__(1024) void scanB_kernel(int* __restrict__ bsum, int nb) {
    int t = threadIdx.x;
    int v = (t < nb) ? bsum[t] : 0;
    __shared__ int sm[1024];
    sm[t] = v;
    __syncthreads();
    for (int s = 1; s < 1024; s <<= 1) {
        int a = (t >= s) ? sm[t - s] : 0;
        __syncthreads();
        sm[t] += a;
        __syncthreads();
    }
    if (t < nb) bsum[t] = sm[t] - v;  // exclusive
}

__global__ __launch_bounds__(256) void scanC_kernel(const int* __restrict__ deg,
                                                    const int* __restrict__ bsum,
                                                    int* __restrict__ off, int n) {
    int t = threadIdx.x;
    int i = blockIdx.x * 256 + t;
    int v = (i < n) ? deg[i] : 0;
    int incl = v;
    int lane = t & 63, wid = t >> 6;
#pragma unroll
    for (int s = 1; s < 64; s <<= 1) {
        int a = __shfl_up(incl, s, 64);
        if (lane >= s) incl += a;
    }
    __shared__ int wsum[4];
    if (lane == 63) wsum[wid] = incl;
    __syncthreads();
    int wo = 0;
    for (int w = 0; w < wid; w++) wo += wsum[w];
    if (i < n) off[i + 1] = bsum[blockIdx.x] + wo + incl;
    if (i == 0) off[0] = 0;
}

__global__ void scatter_kernel(const int* __restrict__ src, const int* __restrict__ dst,
                               int ET, const int* __restrict__ off,
                               int* __restrict__ cursor, int* __restrict__ esrc) {
    int k = blockIdx.x * blockDim.x + threadIdx.x;
    if (k >= ET) return;
    int d = dst[k];
    int p = atomicAdd(&cursor[d], 1);
    esrc[off[d] + p] = src[k];
}

// Merged weight conversion: blocks 0..63 transpose W1 -> w1t (32x32 LDS
// tiles); blocks 64..95 convert W2 -> w2t (transposed, c-major).
__global__ __launch_bounds__(256) void convert_w_kernel(
        const float* __restrict__ W1, const float* __restrict__ W2,
        ushort* __restrict__ w1t, ushort* __restrict__ w2t) {
    int bid = blockIdx.x;
    if (bid < 64) {
        __shared__ float tile[32][33];
        int tx = threadIdx.x & 31, ty = threadIdx.x >> 5;
        int bx = bid & 7, by = bid >> 3;
        for (int i = 0; i < 32; i += 8)
            tile[ty + i][tx] = W1[(by * 32 + ty + i) * 256 + bx * 32 + tx];
        __syncthreads();
        for (int i = 0; i < 32; i += 8)
            w1t[(bx * 32 + ty + i) * 256 + by * 32 + tx] = f2bf(tile[tx][ty + i]);
    } else {
        int idx = (bid - 64) * 256 + threadIdx.x;   // 32 blocks x 256 = 8192
        int c = idx >> 8, k = idx & 255;
        w2t[idx] = f2bf(W2[k * 32 + c]);
    }
}

// h1 = x @ W1 via bf16 MFMA, BN=256 (x read once). 128x256 block tile, BK=64,
// 4 waves (2x2), wave tile 64x128 (4x8 frags). A-staging converts f32->bf16
// in-register. Epilogue writes h1b AND computes as1/ad1 from acc registers
// (head h = col-pair ni{2h,2h+1}; shfl_xor over the 16 col-lanes).
#define LDA 72
__global__ __launch_bounds__(256) void gemm1_mfma(
        const float* __restrict__ x,      // [N][256] f32
        const ushort* __restrict__ w1t,   // [256][256] bf16 (n-major)
        const float* __restrict__ a_src1, const float* __restrict__ a_dst1,
        ushort* __restrict__ h1b,         // [N][256] bf16 out
        float* __restrict__ as1, float* __restrict__ ad1,
        int N) {
    __shared__ ushort Al[128 * LDA];
    __shared__ ushort Bl[256 * LDA];
    int t = threadIdx.x;
    int row0 = blockIdx.x * 128;
    int lane = t & 63, wid = t >> 6;
    int wr = wid >> 1, wc = wid & 1;    // wave tile: rows wr*64+, cols wc*128+

    f32x4 acc[4][8] = {};

    int sr = t >> 1, scs = (t & 1) * 32;   // A staging: row, col-segment
    for (int k0 = 0; k0 < 256; k0 += 64) {
        // stage A tile (128 x 64) f32 -> bf16
        {
            int gr = row0 + sr;
            float4 f[8];
            if (gr < N) {
                const float4* g = (const float4*)(x + (size_t)gr * 256 + k0 + scs);
#pragma unroll
                for (int q = 0; q < 8; q++) f[q] = g[q];
            } else {
#pragma unroll
                for (int q = 0; q < 8; q++) f[q] = float4{0.f, 0.f, 0.f, 0.f};
            }
            uint4* d = (uint4*)&Al[sr * LDA + scs];
#pragma unroll
            for (int p = 0; p < 4; p++) {
                uint4 u;
                u.x = pack2(f[2 * p].x, f[2 * p].y);
                u.y = pack2(f[2 * p].z, f[2 * p].w);
                u.z = pack2(f[2 * p + 1].x, f[2 * p + 1].y);
                u.w = pack2(f[2 * p + 1].z, f[2 * p + 1].w);
                d[p] = u;
            }
        }
        // stage B tile (256 n-rows x 64 k): thread t stages row t (8 uint4)
        {
            const uint4* g = (const uint4*)(w1t + (size_t)t * 256 + k0);
            uint4* d = (uint4*)&Bl[t * LDA];
#pragma unroll
            for (int p = 0; p < 8; p++) d[p] = g[p];
        }
        __syncthreads();

#pragma unroll
        for (int ks = 0; ks < 2; ks++) {
            int kk = ks * 32 + (lane >> 4) * 8;
            bf16x8 af[4];
#pragma unroll
            for (int mi = 0; mi < 4; mi++) {
                int r = wr * 64 + mi * 16 + (lane & 15);
                af[mi] = *(const bf16x8*)&Al[r * LDA + kk];
            }
#pragma unroll
            for (int ni = 0; ni < 8; ni++) {
                int br = wc * 128 + ni * 16 + (lane & 15);
                bf16x8 bfr = *(const bf16x8*)&Bl[br * LDA + kk];
#pragma unroll
                for (int mi = 0; mi < 4; mi++)
                    acc[mi][ni] = __builtin_amdgcn_mfma_f32_16x16x32_bf16(
                        af[mi], bfr, acc[mi][ni], 0, 0, 0);
            }
        }
        __syncthreads();
    }

    int l16 = lane & 15, l4 = lane >> 4;
    // C write (layout m89/m91: col = lane&15, row = (lane>>4)*4 + j)
#pragma unroll
    for (int mi = 0; mi < 4; mi++)
#pragma unroll
        for (int ni = 0; ni < 8; ni++) {
            int gc = wc * 128 + ni * 16 + l16;
#pragma unroll
            for (int j = 0; j < 4; j++) {
                int gr = row0 + wr * 64 + mi * 16 + l4 * 4 + j;
                if (gr < N) h1b[(size_t)gr * 256 + gc] = f2bf(acc[mi][ni][j]);
            }
        }

    // fused alpha1: per lane the a-vectors for its 8 cols
    float sa[8], da[8];
#pragma unroll
    for (int ni = 0; ni < 8; ni++) {
        int c = wc * 128 + ni * 16 + l16;
        sa[ni] = a_src1[c];
        da[ni] = a_dst1[c];
    }
#pragma unroll
    for (int mi = 0; mi < 4; mi++)
#pragma unroll
        for (int j = 0; j < 4; j++) {
            int gr = row0 + wr * 64 + mi * 16 + l4 * 4 + j;
#pragma unroll
            for (int h = 0; h < 4; h++) {   // local head; cols ni=2h,2h+1
                float ps = acc[mi][2 * h][j] * sa[2 * h]
                         + acc[mi][2 * h + 1][j] * sa[2 * h + 1];
                float pd = acc[mi][2 * h][j] * da[2 * h]
                         + acc[mi][2 * h + 1][j] * da[2 * h + 1];
                ps += __shfl_xor(ps, 1); ps += __shfl_xor(ps, 2);
                ps += __shfl_xor(ps, 4); ps += __shfl_xor(ps, 8);
                pd += __shfl_xor(pd, 1); pd += __shfl_xor(pd, 2);
                pd += __shfl_xor(pd, 4); pd += __shfl_xor(pd, 8);
                if (l16 == 0 && gr < N) {
                    as1[gr * 8 + wc * 4 + h] = ps;
                    ad1[gr * 8 + wc * 4 + h] = pd;
                }
            }
        }
}

// Layer-1 FUSED softmax + gather (agg1f). TWO nodes per wave: each 32-lane
// half owns one node, 8 channels/lane via uint4. Phase 1 = single as1 pass ->
// shfl stats -> LDS weights (half-wave private, no barriers). Phase 2 =
// simple 4-wide+tail gather. [FROZEN from R13]
#define FMA8(W, V)                                                      \
    c0 = fmaf(W, bf2f((ushort)((V).x & 0xffffu)), c0);                  \
    c1 = fmaf(W, bf2f((ushort)((V).x >> 16)), c1);                      \
    c2 = fmaf(W, bf2f((ushort)((V).y & 0xffffu)), c2);                  \
    c3 = fmaf(W, bf2f((ushort)((V).y >> 16)), c3);                      \
    c4 = fmaf(W, bf2f((ushort)((V).z & 0xffffu)), c4);                  \
    c5 = fmaf(W, bf2f((ushort)((V).z >> 16)), c5);                      \
    c6 = fmaf(W, bf2f((ushort)((V).w & 0xffffu)), c6);                  \
    c7 = fmaf(W, bf2f((ushort)((V).w >> 16)), c7);

__global__ __launch_bounds__(256) void agg1f_kernel(
        const ushort* __restrict__ h1b,
        const float* __restrict__ as1, const float* __restrict__ ad1,
        const float* __restrict__ b1,
        const int* __restrict__ off, const int* __restrict__ esrc,
        ushort* __restrict__ hactb, int N) {
    __shared__ float s_w[8][32][8];     // 8 KB; [node-slot][edge][head]
    int t = threadIdx.x;
    int slot = t >> 5;                  // node slot 0..7 (2 per wave)
    int node = blockIdx.x * 8 + slot;
    int l = t & 31;                     // lane within half-wave
    if (node >= N) return;
    int beg = off[node], end = off[node + 1];
    int deg = end - beg;
    int h = l & 7, q = l >> 3;          // phase-1 role: edge-slot q (0..3), head h
    float adv = ad1[node * 8 + h];
    int head2 = l >> 2;                 // phase-2 role: 8 ch/lane, head = ch0/32
    int ch0 = l * 8;
    const ushort* hb = h1b + ch0;
    float c0 = 0.f, c1 = 0.f, c2 = 0.f, c3 = 0.f;
    float c4 = 0.f, c5 = 0.f, c6 = 0.f, c7 = 0.f;

    if (deg <= 32) {
        float e_r[8];
#pragma unroll
        for (int r = 0; r < 8; r++) {
            int j = beg + r * 4 + q;
            float e = -3.0e38f;
            if (j < end) {
                e = as1[esrc[j] * 8 + h] + adv;
                e = (e > 0.f) ? e : 0.2f * e;   // leaky_relu(0.2)
            }
            e_r[r] = e;
        }
        float m = e_r[0];
#pragma unroll
        for (int r = 1; r < 8; r++) m = fmaxf(m, e_r[r]);
        m = fmaxf(m, __shfl_xor(m, 8, 32));
        m = fmaxf(m, __shfl_xor(m, 16, 32));
        float dnm = 0.f;
#pragma unroll
        for (int r = 0; r < 8; r++)
            if (beg + r * 4 + q < end) dnm += __expf(e_r[r] - m);
        dnm += __shfl_xor(dnm, 8, 32);
        dnm += __shfl_xor(dnm, 16, 32);
        float inv = 1.f / (dnm + 1e-16f);
#pragma unroll
        for (int r = 0; r < 8; r++) {
            int j = beg + r * 4 + q;
            if (j < end) s_w[slot][r * 4 + q][h] = __expf(e_r[r] - m) * inv;
        }
        const float* wp = &s_w[slot][0][head2];
        int j = beg;
        for (; j + 4 <= end; j += 4) {
            int k = j - beg;
            int s0 = esrc[j + 0], s1 = esrc[j + 1], s2 = esrc[j + 2], s3 = esrc[j + 3];
            float w0 = wp[(k + 0) * 8];
            float w1 = wp[(k + 1) * 8];
            float w2 = wp[(k + 2) * 8];
            float w3 = wp[(k + 3) * 8];
            uint4 v0 = *(const uint4*)(hb + (size_t)s0 * 256);
            uint4 v1 = *(const uint4*)(hb + (size_t)s1 * 256);
            uint4 v2 = *(const uint4*)(hb + (size_t)s2 * 256);
            uint4 v3 = *(const uint4*)(hb + (size_t)s3 * 256);
            FMA8(w0, v0);
            FMA8(w1, v1);
            FMA8(w2, v2);
            FMA8(w3, v3);
        }
        for (; j < end; j++) {
            int s0 = esrc[j];
            float w = wp[(j - beg) * 8];
            uint4 v = *(const uint4*)(hb + (size_t)s0 * 256);
            FMA8(w, v);
        }
    } else {
        float m = -3.0e38f;
        for (int j0 = beg; j0 < end; j0 += 4) {
            int j = j0 + q;
            if (j < end) {
                float e = as1[esrc[j] * 8 + h] + adv;
                e = (e > 0.f) ? e : 0.2f * e;
                m = fmaxf(m, e);
            }
        }
        m = fmaxf(m, __shfl_xor(m, 8, 32));
        m = fmaxf(m, __shfl_xor(m, 16, 32));
        float dnm = 0.f;
        for (int j0 = beg; j0 < end; j0 += 4) {
            int j = j0 + q;
            if (j < end) {
                float e = as1[esrc[j] * 8 + h] + adv;
                e = (e > 0.f) ? e : 0.2f * e;
                dnm += __expf(e - m);
            }
        }
        dnm += __shfl_xor(dnm, 8, 32);
        dnm += __shfl_xor(dnm, 16, 32);
        float inv = 1.f / (dnm + 1e-16f);
        float m2   = __shfl(m, head2, 32);
        float inv2 = __shfl(inv, head2, 32);
        float adv2 = __shfl(adv, head2, 32);
        const float* asp = as1 + head2;
        for (int j = beg; j < end; j++) {
            int s0 = esrc[j];
            float e = asp[s0 * 8] + adv2;
            e = (e > 0.f) ? e : 0.2f * e;
            float w = __expf(e - m2) * inv2;
            uint4 v = *(const uint4*)(hb + (size_t)s0 * 256);
            FMA8(w, v);
        }
    }

    float4 bv0 = *(const float4*)&b1[ch0];
    float4 bv1 = *(const float4*)&b1[ch0 + 4];
    float o0 = c0 + bv0.x, o1 = c1 + bv0.y, o2 = c2 + bv0.z, o3 = c3 + bv0.w;
    float o4 = c4 + bv1.x, o5 = c5 + bv1.y, o6 = c6 + bv1.z, o7 = c7 + bv1.w;
    o0 = (o0 > 0.f) ? o0 : (__expf(o0) - 1.f);
    o1 = (o1 > 0.f) ? o1 : (__expf(o1) - 1.f);
    o2 = (o2 > 0.f) ? o2 : (__expf(o2) - 1.f);
    o3 = (o3 > 0.f) ? o3 : (__expf(o3) - 1.f);
    o4 = (o4 > 0.f) ? o4 : (__expf(o4) - 1.f);
    o5 = (o5 > 0.f) ? o5 : (__expf(o5) - 1.f);
    o6 = (o6 > 0.f) ? o6 : (__expf(o6) - 1.f);
    o7 = (o7 > 0.f) ? o7 : (__expf(o7) - 1.f);
    uint4 r;
    r.x = pack2(o0, o1);
    r.y = pack2(o2, o3);
    r.z = pack2(o4, o5);
    r.w = pack2(o6, o7);
    *(uint4*)(hactb + (size_t)node * 256 + ch0) = r;
}

// h2 = hactb @ W2 via bf16 MFMA. Tile 128x32, BK=64, 4 waves each owning a
// 32x32 m-subtile (2x2 frags). Output f32. Epilogue also computes as2/ad2
// from acc registers (fused alpha2).
__global__ __launch_bounds__(256) void gemm2_mfma(
        const ushort* __restrict__ hactb,  // [N][256] bf16
        const ushort* __restrict__ w2t,    // [32][256] bf16 (c-major)
        const float* __restrict__ a_src2, const float* __restrict__ a_dst2,
        float* __restrict__ h2,
        float* __restrict__ as2, float* __restrict__ ad2, int N) {
    __shared__ ushort Al[128 * LDA];
    __shared__ ushort Bl[32 * LDA];
    int t = threadIdx.x;
    int row0 = blockIdx.x * 128;
    int lane = t & 63, wid = t >> 6;

    f32x4 acc[2][2] = {};

    int sr = t >> 1, scs = (t & 1) * 32;
    for (int k0 = 0; k0 < 256; k0 += 64) {
        {
            int gr = row0 + sr;
            uint4 v0 = {0,0,0,0}, v1 = {0,0,0,0}, v2 = {0,0,0,0}, v3 = {0,0,0,0};
            if (gr < N) {
                const uint4* g = (const uint4*)(hactb + (size_t)gr * 256 + k0 + scs);
                v0 = g[0]; v1 = g[1]; v2 = g[2]; v3 = g[3];
            }
            uint4* d = (uint4*)&Al[sr * LDA + scs];
            d[0] = v0; d[1] = v1; d[2] = v2; d[3] = v3;
        }
        if (t < 64) {
            const uint4* g = (const uint4*)(w2t + (size_t)sr * 256 + k0 + scs);
            uint4* d = (uint4*)&Bl[sr * LDA + scs];
            d[0] = g[0]; d[1] = g[1]; d[2] = g[2]; d[3] = g[3];
        }
        __syncthreads();

#pragma unroll
        for (int ks = 0; ks < 2; ks++) {
            int kk = ks * 32 + (lane >> 4) * 8;
            bf16x8 af[2], bfr[2];
#pragma unroll
            for (int mi = 0; mi < 2; mi++) {
                int r = wid * 32 + mi * 16 + (lane & 15);
                af[mi] = *(const bf16x8*)&Al[r * LDA + kk];
            }
#pragma unroll
            for (int ni = 0; ni < 2; ni++) {
                int r = ni * 16 + (lane & 15);
                bfr[ni] = *(const bf16x8*)&Bl[r * LDA + kk];
            }
#pragma unroll
            for (int mi = 0; mi < 2; mi++)
#pragma unroll
                for (int ni = 0; ni < 2; ni++)
                    acc[mi][ni] = __builtin_amdgcn_mfma_f32_16x16x32_bf16(
                        af[mi], bfr[ni], acc[mi][ni], 0, 0, 0);
        }
        __syncthreads();
    }

    int l16 = lane & 15, l4 = lane >> 4;
#pragma unroll
    for (int mi = 0; mi < 2; mi++)
#pragma unroll
        for (int ni = 0; ni < 2; ni++) {
            int gc = ni * 16 + l16;
#pragma unroll
            for (int j = 0; j < 4; j++) {
                int gr = row0 + wid * 32 + mi * 16 + l4 * 4 + j;
                if (gr < N) h2[(size_t)gr * 32 + gc] = acc[mi][ni][j];
            }
        }

    // fused alpha2: dot over all 32 cols (ni=0,1 x 16 lanes)
    float sa0 = a_src2[l16], sa1 = a_src2[16 + l16];
    float da0 = a_dst2[l16], da1 = a_dst2[16 + l16];
#pragma unroll
    for (int mi = 0; mi < 2; mi++)
#pragma unroll
        for (int j = 0; j < 4; j++) {
            int gr = row0 + wid * 32 + mi * 16 + l4 * 4 + j;
            float ps = acc[mi][0][j] * sa0 + acc[mi][1][j] * sa1;
            float pd = acc[mi][0][j] * da0 + acc[mi][1][j] * da1;
            ps += __shfl_xor(ps, 1); ps += __shfl_xor(ps, 2);
            ps += __shfl_xor(ps, 4); ps += __shfl_xor(ps, 8);
            pd += __shfl_xor(pd, 1); pd += __shfl_xor(pd, 2);
            pd += __shfl_xor(pd, 4); pd += __shfl_xor(pd, 8);
            if (l16 == 0 && gr < N) {
                as2[gr] = ps;
                ad2[gr] = pd;
            }
        }
}

// Layer-2 FUSED softmax + gather + bias + log_softmax (agg2f). [FROZEN R15]
__global__ __launch_bounds__(256) void agg2f_kernel(
        const float* __restrict__ h2,
        const float* __restrict__ as2, const float* __restrict__ ad2,
        const float* __restrict__ b2,
        const int* __restrict__ off, const int* __restrict__ esrc,
        float* __restrict__ out, int N) {
    __shared__ float s_w[8][32];        // 1 KB; [group][edge]
    int t = threadIdx.x;
    int g = t >> 5, c = t & 31;
    int node = blockIdx.x * 8 + g;
    if (node >= N) return;
    int beg = off[node], end = off[node + 1];
    int deg = end - beg;
    float adv = ad2[node];
    const float* hcol = h2 + c;
    float a0 = 0.f, a1 = 0.f, a2 = 0.f, a3 = 0.f;

    if (deg <= 32) {
        float e = -3.0e38f;
        if (c < deg) {
            float v = as2[esrc[beg + c]] + adv;
            e = (v > 0.f) ? v : 0.2f * v;   // leaky_relu(0.2)
        }
        float m = e;
#pragma unroll
        for (int s = 16; s > 0; s >>= 1) m = fmaxf(m, __shfl_xor(m, s, 32));
        float w = (c < deg) ? __expf(e - m) : 0.f;
        float dn = w;
#pragma unroll
        for (int s = 16; s > 0; s >>= 1) dn += __shfl_xor(dn, s, 32);
        s_w[g][c] = w * (1.f / (dn + 1e-16f));
        int j = beg;
        for (; j + 4 <= end; j += 4) {
            int k = j - beg;
            int s0 = esrc[j + 0], s1 = esrc[j + 1], s2 = esrc[j + 2], s3 = esrc[j + 3];
            float w0 = s_w[g][k + 0];
            float w1 = s_w[g][k + 1];
            float w2 = s_w[g][k + 2];
            float w3 = s_w[g][k + 3];
            a0 = fmaf(w0, hcol[(size_t)s0 * 32], a0);
            a1 = fmaf(w1, hcol[(size_t)s1 * 32], a1);
            a2 = fmaf(w2, hcol[(size_t)s2 * 32], a2);
            a3 = fmaf(w3, hcol[(size_t)s3 * 32], a3);
        }
        for (; j < end; j++)
            a0 = fmaf(s_w[g][j - beg], hcol[(size_t)esrc[j] * 32], a0);
    } else {
        float m = -3.0e38f, dnm = 0.f;
        for (int base = beg; base < end; base += 32) {
            int n_ch = min(32, end - base);
            float ej = -3.0e38f;
            if (c < n_ch) {
                float e = as2[esrc[base + c]] + adv;
                ej = (e > 0.f) ? e : 0.2f * e;
            }
            float cm = ej;
#pragma unroll
            for (int s = 16; s > 0; s >>= 1) cm = fmaxf(cm, __shfl_xor(cm, s, 32));
            float nm = fmaxf(m, cm);
            float scl = __expf(m - nm);
            float wj = (c < n_ch) ? __expf(ej - nm) : 0.f;
            float ws = wj;
#pragma unroll
            for (int s = 16; s > 0; s >>= 1) ws += __shfl_xor(ws, s, 32);
            dnm = dnm * scl + ws;
            m = nm;
        }
        float inv = 1.f / (dnm + 1e-16f);
        int j = beg;
        for (; j + 4 <= end; j += 4) {
            int s0 = esrc[j + 0], s1 = esrc[j + 1], s2 = esrc[j + 2], s3 = esrc[j + 3];
            float e0 = as2[s0] + adv, e1 = as2[s1] + adv;
            float e2 = as2[s2] + adv, e3 = as2[s3] + adv;
            e0 = (e0 > 0.f) ? e0 : 0.2f * e0;
            e1 = (e1 > 0.f) ? e1 : 0.2f * e1;
            e2 = (e2 > 0.f) ? e2 : 0.2f * e2;
            e3 = (e3 > 0.f) ? e3 : 0.2f * e3;
            float w0 = __expf(e0 - m) * inv, w1 = __expf(e1 - m) * inv;
            float w2 = __expf(e2 - m) * inv, w3 = __expf(e3 - m) * inv;
            a0 = fmaf(w0, hcol[(size_t)s0 * 32], a0);
            a1 = fmaf(w1, hcol[(size_t)s1 * 32], a1);
            a2 = fmaf(w2, hcol[(size_t)s2 * 32], a2);
            a3 = fmaf(w3, hcol[(size_t)s3 * 32], a3);
        }
        for (; j < end; j++) {
            int s0 = esrc[j];
            float e = as2[s0] + adv;
            e = (e > 0.f) ? e : 0.2f * e;
            a0 = fmaf(__expf(e - m) * inv, hcol[(size_t)s0 * 32], a0);
        }
    }

    float v = (a0 + a1) + (a2 + a3) + b2[c];
    float mx = v;
#pragma unroll
    for (int s = 16; s > 0; s >>= 1) mx = fmaxf(mx, __shfl_xor(mx, s, 32));
    float sum = __expf(v - mx);
#pragma unroll
    for (int s = 16; s > 0; s >>= 1) sum += __shfl_xor(sum, s, 32);
    out[(size_t)node * 32 + c] = (v - mx) - __logf(sum);
}

extern "C" void kernel_launch(void* const* d_in, const int* in_sizes, int n_in,
                              void* d_out, int out_size, void* d_ws, size_t ws_size,
                              hipStream_t stream) {
    const float* x      = (const float*)d_in[0];
    const void*  ei     = d_in[1];
    const float* W1     = (const float*)d_in[2];
    const float* a_src1 = (const float*)d_in[3];
    const float* a_dst1 = (const float*)d_in[4];
    const float* b1     = (const float*)d_in[5];
    const float* W2     = (const float*)d_in[6];
    const float* a_src2 = (const float*)d_in[7];
    const float* a_dst2 = (const float*)d_in[8];
    const float* b2     = (const float*)d_in[9];
    const int N  = in_sizes[0] / 256;   // 50000
    const int E  = in_sizes[1] / 2;     // 500000
    const int ET = E + N;
    float* outp = (float*)d_out;
    (void)n_in; (void)out_size; (void)ws_size;

    char* ws = (char*)d_ws;
    size_t o = 0;
    auto alloc = [&](size_t bytes) -> void* {
        void* p = ws + o;
        o += (bytes + 255) & ~(size_t)255;
        return p;
    };
    int*    flag   = (int*)alloc(4);
    int*    src32  = (int*)alloc((size_t)ET * 4);
    int*    dst32  = (int*)alloc((size_t)ET * 4);
    int*    deg    = (int*)alloc((size_t)2 * N * 4);  // deg + cursor, one memset
    int*    cursor = deg + N;
    int*    off    = (int*)alloc((size_t)(N + 1) * 4);
    int*    esrc   = (int*)alloc((size_t)ET * 4);
    int*    bsum   = (int*)alloc((size_t)1024 * 4);
    ushort* w1t    = (ushort*)alloc((size_t)256 * 256 * 2);
    ushort* w2t    = (ushort*)alloc((size_t)32 * 256 * 2);
    ushort* h1b    = (ushort*)alloc((size_t)N * 256 * 2);
    float*  as1    = (float*)alloc((size_t)N * 8 * 4);
    float*  ad1    = (float*)alloc((size_t)N * 8 * 4);
    ushort* hactb  = (ushort*)alloc((size_t)N * 256 * 2);
    float*  h2     = (float*)alloc((size_t)N * 32 * 4);
    float*  as2    = (float*)alloc((size_t)N * 4);
    float*  ad2    = (float*)alloc((size_t)N * 4);

    const int nbScan = (N + 255) / 256;   // 196

    hipMemsetAsync(deg, 0, (size_t)2 * N * 4, stream);
    detect_kernel<<<1, 256, 0, stream>>>((const int*)ei, flag);
    decode_degree_kernel<<<(ET + 255) / 256, 256, 0, stream>>>(ei, E, ET, N, flag,
                                                               src32, dst32, deg);
    scanA_kernel<<<nbScan, 256, 0, stream>>>(deg, bsum, N);
    scanB_kernel<<<1, 1024, 0, stream>>>(bsum, nbScan);
    scanC_kernel<<<nbScan, 256, 0, stream>>>(deg, bsum, off, N);
    scatter_kernel<<<(ET + 255) / 256, 256, 0, stream>>>(src32, dst32, ET, off,
                                                         cursor, esrc);

    convert_w_kernel<<<96, 256, 0, stream>>>(W1, W2, w1t, w2t);

    gemm1_mfma<<<(N + 127) / 128, 256, 0, stream>>>(x, w1t, a_src1, a_dst1,
                                                    h1b, as1, ad1, N);
    agg1f_kernel<<<(N + 7) / 8, 256, 0, stream>>>(h1b, as1, ad1, b1, off, esrc,
                                                  hactb, N);
    gemm2_mfma<<<(N + 127) / 128, 256, 0, stream>>>(hactb, w2t, a_src2, a_dst2,
                                                    h2, as2, ad2, N);
    agg2f_kernel<<<(N + 7) / 8, 256, 0, stream>>>(h2, as2, ad2, b2, off, esrc,
                                                  outp, N);
}

// Round 18
// 203.777 us; speedup vs baseline: 1.0480x; 1.0480x over previous
//
#include <hip/hip_runtime.h>
#include <math.h>

// ---------------------------------------------------------------------------
// GAT 2-layer forward (N=50000, F_in=256, H1=8, C1=32, C2=32, E=500000).
// R17: gemm1 BN=256 REVERTED (55KB LDS -> 7.9% occupancy -> 65us; classic
// occupancy cliff). Back to R15's proven 128x128/y-grid-2 geometry (36KB LDS,
// ~60% occ), KEEPING the alpha1 epilogue fusion (register math only — each
// y-block covers heads y*4+wc*2+{0,1}). gemm2 keeps fused alpha2. agg1f,
// agg2f, CSR chain, convert_w frozen.
// ---------------------------------------------------------------------------

typedef __attribute__((ext_vector_type(8))) short bf16x8;
typedef __attribute__((ext_vector_type(4))) float f32x4;

__device__ __forceinline__ float bf2f(ushort u) {
    union { uint i; float f; } v; v.i = ((uint)u) << 16; return v.f;
}
__device__ __forceinline__ ushort f2bf(float f) {  // round-to-nearest-even
    union { float f; uint i; } v; v.f = f;
    uint r = v.i + 0x7FFFu + ((v.i >> 16) & 1u);
    return (ushort)(r >> 16);
}
__device__ __forceinline__ uint pack2(float a, float b) {
    return (uint)f2bf(a) | ((uint)f2bf(b) << 16);
}

// int64 little-endian values < 2^31 => every odd 32-bit word is 0.
__global__ void detect_kernel(const int* ei32, int* flag) {
    __shared__ int cnt;
    if (threadIdx.x == 0) cnt = 0;
    __syncthreads();
    int nz = 0;
    for (int i = threadIdx.x; i < 1024; i += blockDim.x)
        if (ei32[2 * i + 1] != 0) nz++;
    atomicAdd(&cnt, nz);
    __syncthreads();
    if (threadIdx.x == 0) *flag = (cnt > 16) ? 1 : 0;  // 1 => int32 layout
}

__global__ void decode_degree_kernel(const void* ei, int E, int ET, int N,
                                     const int* __restrict__ flag,
                                     int* __restrict__ src, int* __restrict__ dst,
                                     int* __restrict__ deg) {
    int k = blockIdx.x * blockDim.x + threadIdx.x;
    if (k >= ET) return;
    int s, d;
    if (k < E) {
        if (*flag) {
            const int* p = (const int*)ei;
            s = p[k]; d = p[E + k];
        } else {
            const long long* p = (const long long*)ei;
            s = (int)p[k]; d = (int)p[E + k];
        }
    } else {
        s = d = k - E;  // self-loops appended
    }
    s = min(max(s, 0), N - 1);
    d = min(max(d, 0), N - 1);
    src[k] = s; dst[k] = d;
    atomicAdd(&deg[d], 1);
}

// --- 3-phase hierarchical exclusive scan (coalesced, parallel) -------------
__global__ __launch_bounds__(256) void scanA_kernel(const int* __restrict__ deg,
                                                    int* __restrict__ bsum, int n) {
    int i = blockIdx.x * 256 + threadIdx.x;
    int v = (i < n) ? deg[i] : 0;
#pragma unroll
    for (int s = 1; s < 64; s <<= 1) v += __shfl_xor(v, s, 64);
    __shared__ int ws[4];
    int lane = threadIdx.x & 63, wid = threadIdx.x >> 6;
    if (lane == 0) ws[wid] = v;
    __syncthreads();
    if (threadIdx.x == 0) bsum[blockIdx.x] = ws[0] + ws[1] + ws[2] + ws[3];
}

__global__ __launch_bounds__(1024) void scanB_kernel(int* __restrict__ bsum, int nb) {
    int t = threadIdx.x;
    int v = (t < nb) ? bsum[t] : 0;
    __shared__ int sm[1024];
    sm[t] = v;
    __syncthreads();
    for (int s = 1; s < 1024; s <<= 1) {
        int a = (t >= s) ? sm[t - s] : 0;
        __syncthreads();
        sm[t] += a;
        __syncthreads();
    }
    if (t < nb) bsum[t] = sm[t] - v;  // exclusive
}

__global__ __launch_bounds__(256) void scanC_kernel(const int* __restrict__ deg,
                                                    const int* __restrict__ bsum,
                                                    int* __restrict__ off, int n) {
    int t = threadIdx.x;
    int i = blockIdx.x * 256 + t;
    int v = (i < n) ? deg[i] : 0;
    int incl = v;
    int lane = t & 63, wid = t >> 6;
#pragma unroll
    for (int s = 1; s < 64; s <<= 1) {
        int a = __shfl_up(incl, s, 64);
        if (lane >= s) incl += a;
    }
    __shared__ int wsum[4];
    if (lane == 63) wsum[wid] = incl;
    __syncthreads();
    int wo = 0;
    for (int w = 0; w < wid; w++) wo += wsum[w];
    if (i < n) off[i + 1] = bsum[blockIdx.x] + wo + incl;
    if (i == 0) off[0] = 0;
}

__global__ void scatter_kernel(const int* __restrict__ src, const int* __restrict__ dst,
                               int ET, const int* __restrict__ off,
                               int* __restrict__ cursor, int* __restrict__ esrc) {
    int k = blockIdx.x * blockDim.x + threadIdx.x;
    if (k >= ET) return;
    int d = dst[k];
    int p = atomicAdd(&cursor[d], 1);
    esrc[off[d] + p] = src[k];
}

// Merged weight conversion: blocks 0..63 transpose W1 -> w1t (32x32 LDS
// tiles); blocks 64..95 convert W2 -> w2t (transposed, c-major).
__global__ __launch_bounds__(256) void convert_w_kernel(
        const float* __restrict__ W1, const float* __restrict__ W2,
        ushort* __restrict__ w1t, ushort* __restrict__ w2t) {
    int bid = blockIdx.x;
    if (bid < 64) {
        __shared__ float tile[32][33];
        int tx = threadIdx.x & 31, ty = threadIdx.x >> 5;
        int bx = bid & 7, by = bid >> 3;
        for (int i = 0; i < 32; i += 8)
            tile[ty + i][tx] = W1[(by * 32 + ty + i) * 256 + bx * 32 + tx];
        __syncthreads();
        for (int i = 0; i < 32; i += 8)
            w1t[(bx * 32 + ty + i) * 256 + by * 32 + tx] = f2bf(tile[tx][ty + i]);
    } else {
        int idx = (bid - 64) * 256 + threadIdx.x;   // 32 blocks x 256 = 8192
        int c = idx >> 8, k = idx & 255;
        w2t[idx] = f2bf(W2[k * 32 + c]);
    }
}

// h1 = x @ W1 via bf16 MFMA. 128x128 tile (y-grid=2 for the 256 cols), BK=64,
// 4 waves (2x2), 4x4 frags — R15's proven geometry (36KB LDS, high occupancy).
// A-staging converts f32->bf16 in-register. Epilogue writes h1b AND computes
// as1/ad1 for this block's heads (y*4 + wc*2 + h) from acc registers.
#define LDA 72
__global__ __launch_bounds__(256) void gemm1_mfma(
        const float* __restrict__ x,      // [N][256] f32
        const ushort* __restrict__ w1t,   // [256][256] bf16 (n-major)
        const float* __restrict__ a_src1, const float* __restrict__ a_dst1,
        ushort* __restrict__ h1b,         // [N][256] bf16 out
        float* __restrict__ as1, float* __restrict__ ad1,
        int N) {
    __shared__ ushort Al[128 * LDA];
    __shared__ ushort Bl[128 * LDA];
    int t = threadIdx.x;
    int row0 = blockIdx.x * 128;
    int n0 = blockIdx.y * 128;
    int lane = t & 63, wid = t >> 6;
    int wr = wid >> 1, wc = wid & 1;

    f32x4 acc[4][4] = {};

    int sr = t >> 1, scs = (t & 1) * 32;
    for (int k0 = 0; k0 < 256; k0 += 64) {
        // stage A tile (128 x 64) f32 -> bf16
        {
            int gr = row0 + sr;
            float4 f[8];
            if (gr < N) {
                const float4* g = (const float4*)(x + (size_t)gr * 256 + k0 + scs);
#pragma unroll
                for (int q = 0; q < 8; q++) f[q] = g[q];
            } else {
#pragma unroll
                for (int q = 0; q < 8; q++) f[q] = float4{0.f, 0.f, 0.f, 0.f};
            }
            uint4* d = (uint4*)&Al[sr * LDA + scs];
#pragma unroll
            for (int p = 0; p < 4; p++) {
                uint4 u;
                u.x = pack2(f[2 * p].x, f[2 * p].y);
                u.y = pack2(f[2 * p].z, f[2 * p].w);
                u.z = pack2(f[2 * p + 1].x, f[2 * p + 1].y);
                u.w = pack2(f[2 * p + 1].z, f[2 * p + 1].w);
                d[p] = u;
            }
        }
        // stage B tile (128 n-rows x 64 k) from pre-transposed w1t
        {
            const uint4* g = (const uint4*)(w1t + (size_t)(n0 + sr) * 256 + k0 + scs);
            uint4* d = (uint4*)&Bl[sr * LDA + scs];
            d[0] = g[0]; d[1] = g[1]; d[2] = g[2]; d[3] = g[3];
        }
        __syncthreads();

#pragma unroll
        for (int ks = 0; ks < 2; ks++) {
            int kk = ks * 32 + (lane >> 4) * 8;
            bf16x8 af[4], bfr[4];
#pragma unroll
            for (int mi = 0; mi < 4; mi++) {
                int r = wr * 64 + mi * 16 + (lane & 15);
                af[mi] = *(const bf16x8*)&Al[r * LDA + kk];
            }
#pragma unroll
            for (int ni = 0; ni < 4; ni++) {
                int r = wc * 64 + ni * 16 + (lane & 15);
                bfr[ni] = *(const bf16x8*)&Bl[r * LDA + kk];
            }
#pragma unroll
            for (int mi = 0; mi < 4; mi++)
#pragma unroll
                for (int ni = 0; ni < 4; ni++)
                    acc[mi][ni] = __builtin_amdgcn_mfma_f32_16x16x32_bf16(
                        af[mi], bfr[ni], acc[mi][ni], 0, 0, 0);
        }
        __syncthreads();
    }

    int l16 = lane & 15, l4 = lane >> 4;
    // C write (layout m89/m91: col = lane&15, row = (lane>>4)*4 + j)
#pragma unroll
    for (int mi = 0; mi < 4; mi++)
#pragma unroll
        for (int ni = 0; ni < 4; ni++) {
            int gc = n0 + wc * 64 + ni * 16 + l16;
#pragma unroll
            for (int j = 0; j < 4; j++) {
                int gr = row0 + wr * 64 + mi * 16 + l4 * 4 + j;
                if (gr < N) h1b[(size_t)gr * 256 + gc] = f2bf(acc[mi][ni][j]);
            }
        }

    // fused alpha1: this block's cols cover heads y*4 + wc*2 + {0,1}
    float sa[4], da[4];
#pragma unroll
    for (int ni = 0; ni < 4; ni++) {
        int c = n0 + wc * 64 + ni * 16 + l16;
        sa[ni] = a_src1[c];
        da[ni] = a_dst1[c];
    }
    int hbase = blockIdx.y * 4 + wc * 2;
#pragma unroll
    for (int mi = 0; mi < 4; mi++)
#pragma unroll
        for (int j = 0; j < 4; j++) {
            int gr = row0 + wr * 64 + mi * 16 + l4 * 4 + j;
#pragma unroll
            for (int h = 0; h < 2; h++) {   // local head; cols ni=2h,2h+1
                float ps = acc[mi][2 * h][j] * sa[2 * h]
                         + acc[mi][2 * h + 1][j] * sa[2 * h + 1];
                float pd = acc[mi][2 * h][j] * da[2 * h]
                         + acc[mi][2 * h + 1][j] * da[2 * h + 1];
                ps += __shfl_xor(ps, 1); ps += __shfl_xor(ps, 2);
                ps += __shfl_xor(ps, 4); ps += __shfl_xor(ps, 8);
                pd += __shfl_xor(pd, 1); pd += __shfl_xor(pd, 2);
                pd += __shfl_xor(pd, 4); pd += __shfl_xor(pd, 8);
                if (l16 == 0 && gr < N) {
                    as1[gr * 8 + hbase + h] = ps;
                    ad1[gr * 8 + hbase + h] = pd;
                }
            }
        }
}

// Layer-1 FUSED softmax + gather (agg1f). TWO nodes per wave: each 32-lane
// half owns one node, 8 channels/lane via uint4. Phase 1 = single as1 pass ->
// shfl stats -> LDS weights (half-wave private, no barriers). Phase 2 =
// simple 4-wide+tail gather. [FROZEN from R13]
#define FMA8(W, V)                                                      \
    c0 = fmaf(W, bf2f((ushort)((V).x & 0xffffu)), c0);                  \
    c1 = fmaf(W, bf2f((ushort)((V).x >> 16)), c1);                      \
    c2 = fmaf(W, bf2f((ushort)((V).y & 0xffffu)), c2);                  \
    c3 = fmaf(W, bf2f((ushort)((V).y >> 16)), c3);                      \
    c4 = fmaf(W, bf2f((ushort)((V).z & 0xffffu)), c4);                  \
    c5 = fmaf(W, bf2f((ushort)((V).z >> 16)), c5);                      \
    c6 = fmaf(W, bf2f((ushort)((V).w & 0xffffu)), c6);                  \
    c7 = fmaf(W, bf2f((ushort)((V).w >> 16)), c7);

__global__ __launch_bounds__(256) void agg1f_kernel(
        const ushort* __restrict__ h1b,
        const float* __restrict__ as1, const float* __restrict__ ad1,
        const float* __restrict__ b1,
        const int* __restrict__ off, const int* __restrict__ esrc,
        ushort* __restrict__ hactb, int N) {
    __shared__ float s_w[8][32][8];     // 8 KB; [node-slot][edge][head]
    int t = threadIdx.x;
    int slot = t >> 5;                  // node slot 0..7 (2 per wave)
    int node = blockIdx.x * 8 + slot;
    int l = t & 31;                     // lane within half-wave
    if (node >= N) return;
    int beg = off[node], end = off[node + 1];
    int deg = end - beg;
    int h = l & 7, q = l >> 3;          // phase-1 role: edge-slot q (0..3), head h
    float adv = ad1[node * 8 + h];
    int head2 = l >> 2;                 // phase-2 role: 8 ch/lane, head = ch0/32
    int ch0 = l * 8;
    const ushort* hb = h1b + ch0;
    float c0 = 0.f, c1 = 0.f, c2 = 0.f, c3 = 0.f;
    float c4 = 0.f, c5 = 0.f, c6 = 0.f, c7 = 0.f;

    if (deg <= 32) {
        float e_r[8];
#pragma unroll
        for (int r = 0; r < 8; r++) {
            int j = beg + r * 4 + q;
            float e = -3.0e38f;
            if (j < end) {
                e = as1[esrc[j] * 8 + h] + adv;
                e = (e > 0.f) ? e : 0.2f * e;   // leaky_relu(0.2)
            }
            e_r[r] = e;
        }
        float m = e_r[0];
#pragma unroll
        for (int r = 1; r < 8; r++) m = fmaxf(m, e_r[r]);
        m = fmaxf(m, __shfl_xor(m, 8, 32));
        m = fmaxf(m, __shfl_xor(m, 16, 32));
        float dnm = 0.f;
#pragma unroll
        for (int r = 0; r < 8; r++)
            if (beg + r * 4 + q < end) dnm += __expf(e_r[r] - m);
        dnm += __shfl_xor(dnm, 8, 32);
        dnm += __shfl_xor(dnm, 16, 32);
        float inv = 1.f / (dnm + 1e-16f);
#pragma unroll
        for (int r = 0; r < 8; r++) {
            int j = beg + r * 4 + q;
            if (j < end) s_w[slot][r * 4 + q][h] = __expf(e_r[r] - m) * inv;
        }
        const float* wp = &s_w[slot][0][head2];
        int j = beg;
        for (; j + 4 <= end; j += 4) {
            int k = j - beg;
            int s0 = esrc[j + 0], s1 = esrc[j + 1], s2 = esrc[j + 2], s3 = esrc[j + 3];
            float w0 = wp[(k + 0) * 8];
            float w1 = wp[(k + 1) * 8];
            float w2 = wp[(k + 2) * 8];
            float w3 = wp[(k + 3) * 8];
            uint4 v0 = *(const uint4*)(hb + (size_t)s0 * 256);
            uint4 v1 = *(const uint4*)(hb + (size_t)s1 * 256);
            uint4 v2 = *(const uint4*)(hb + (size_t)s2 * 256);
            uint4 v3 = *(const uint4*)(hb + (size_t)s3 * 256);
            FMA8(w0, v0);
            FMA8(w1, v1);
            FMA8(w2, v2);
            FMA8(w3, v3);
        }
        for (; j < end; j++) {
            int s0 = esrc[j];
            float w = wp[(j - beg) * 8];
            uint4 v = *(const uint4*)(hb + (size_t)s0 * 256);
            FMA8(w, v);
        }
    } else {
        float m = -3.0e38f;
        for (int j0 = beg; j0 < end; j0 += 4) {
            int j = j0 + q;
            if (j < end) {
                float e = as1[esrc[j] * 8 + h] + adv;
                e = (e > 0.f) ? e : 0.2f * e;
                m = fmaxf(m, e);
            }
        }
        m = fmaxf(m, __shfl_xor(m, 8, 32));
        m = fmaxf(m, __shfl_xor(m, 16, 32));
        float dnm = 0.f;
        for (int j0 = beg; j0 < end; j0 += 4) {
            int j = j0 + q;
            if (j < end) {
                float e = as1[esrc[j] * 8 + h] + adv;
                e = (e > 0.f) ? e : 0.2f * e;
                dnm += __expf(e - m);
            }
        }
        dnm += __shfl_xor(dnm, 8, 32);
        dnm += __shfl_xor(dnm, 16, 32);
        float inv = 1.f / (dnm + 1e-16f);
        float m2   = __shfl(m, head2, 32);
        float inv2 = __shfl(inv, head2, 32);
        float adv2 = __shfl(adv, head2, 32);
        const float* asp = as1 + head2;
        for (int j = beg; j < end; j++) {
            int s0 = esrc[j];
            float e = asp[s0 * 8] + adv2;
            e = (e > 0.f) ? e : 0.2f * e;
            float w = __expf(e - m2) * inv2;
            uint4 v = *(const uint4*)(hb + (size_t)s0 * 256);
            FMA8(w, v);
        }
    }

    float4 bv0 = *(const float4*)&b1[ch0];
    float4 bv1 = *(const float4*)&b1[ch0 + 4];
    float o0 = c0 + bv0.x, o1 = c1 + bv0.y, o2 = c2 + bv0.z, o3 = c3 + bv0.w;
    float o4 = c4 + bv1.x, o5 = c5 + bv1.y, o6 = c6 + bv1.z, o7 = c7 + bv1.w;
    o0 = (o0 > 0.f) ? o0 : (__expf(o0) - 1.f);
    o1 = (o1 > 0.f) ? o1 : (__expf(o1) - 1.f);
    o2 = (o2 > 0.f) ? o2 : (__expf(o2) - 1.f);
    o3 = (o3 > 0.f) ? o3 : (__expf(o3) - 1.f);
    o4 = (o4 > 0.f) ? o4 : (__expf(o4) - 1.f);
    o5 = (o5 > 0.f) ? o5 : (__expf(o5) - 1.f);
    o6 = (o6 > 0.f) ? o6 : (__expf(o6) - 1.f);
    o7 = (o7 > 0.f) ? o7 : (__expf(o7) - 1.f);
    uint4 r;
    r.x = pack2(o0, o1);
    r.y = pack2(o2, o3);
    r.z = pack2(o4, o5);
    r.w = pack2(o6, o7);
    *(uint4*)(hactb + (size_t)node * 256 + ch0) = r;
}

// h2 = hactb @ W2 via bf16 MFMA. Tile 128x32, BK=64, 4 waves each owning a
// 32x32 m-subtile (2x2 frags). Output f32. Epilogue computes as2/ad2 from acc
// registers (fused alpha2).
__global__ __launch_bounds__(256) void gemm2_mfma(
        const ushort* __restrict__ hactb,  // [N][256] bf16
        const ushort* __restrict__ w2t,    // [32][256] bf16 (c-major)
        const float* __restrict__ a_src2, const float* __restrict__ a_dst2,
        float* __restrict__ h2,
        float* __restrict__ as2, float* __restrict__ ad2, int N) {
    __shared__ ushort Al[128 * LDA];
    __shared__ ushort Bl[32 * LDA];
    int t = threadIdx.x;
    int row0 = blockIdx.x * 128;
    int lane = t & 63, wid = t >> 6;

    f32x4 acc[2][2] = {};

    int sr = t >> 1, scs = (t & 1) * 32;
    for (int k0 = 0; k0 < 256; k0 += 64) {
        {
            int gr = row0 + sr;
            uint4 v0 = {0,0,0,0}, v1 = {0,0,0,0}, v2 = {0,0,0,0}, v3 = {0,0,0,0};
            if (gr < N) {
                const uint4* g = (const uint4*)(hactb + (size_t)gr * 256 + k0 + scs);
                v0 = g[0]; v1 = g[1]; v2 = g[2]; v3 = g[3];
            }
            uint4* d = (uint4*)&Al[sr * LDA + scs];
            d[0] = v0; d[1] = v1; d[2] = v2; d[3] = v3;
        }
        if (t < 64) {
            const uint4* g = (const uint4*)(w2t + (size_t)sr * 256 + k0 + scs);
            uint4* d = (uint4*)&Bl[sr * LDA + scs];
            d[0] = g[0]; d[1] = g[1]; d[2] = g[2]; d[3] = g[3];
        }
        __syncthreads();

#pragma unroll
        for (int ks = 0; ks < 2; ks++) {
            int kk = ks * 32 + (lane >> 4) * 8;
            bf16x8 af[2], bfr[2];
#pragma unroll
            for (int mi = 0; mi < 2; mi++) {
                int r = wid * 32 + mi * 16 + (lane & 15);
                af[mi] = *(const bf16x8*)&Al[r * LDA + kk];
            }
#pragma unroll
            for (int ni = 0; ni < 2; ni++) {
                int r = ni * 16 + (lane & 15);
                bfr[ni] = *(const bf16x8*)&Bl[r * LDA + kk];
            }
#pragma unroll
            for (int mi = 0; mi < 2; mi++)
#pragma unroll
                for (int ni = 0; ni < 2; ni++)
                    acc[mi][ni] = __builtin_amdgcn_mfma_f32_16x16x32_bf16(
                        af[mi], bfr[ni], acc[mi][ni], 0, 0, 0);
        }
        __syncthreads();
    }

    int l16 = lane & 15, l4 = lane >> 4;
#pragma unroll
    for (int mi = 0; mi < 2; mi++)
#pragma unroll
        for (int ni = 0; ni < 2; ni++) {
            int gc = ni * 16 + l16;
#pragma unroll
            for (int j = 0; j < 4; j++) {
                int gr = row0 + wid * 32 + mi * 16 + l4 * 4 + j;
                if (gr < N) h2[(size_t)gr * 32 + gc] = acc[mi][ni][j];
            }
        }

    // fused alpha2: dot over all 32 cols (ni=0,1 x 16 lanes)
    float sa0 = a_src2[l16], sa1 = a_src2[16 + l16];
    float da0 = a_dst2[l16], da1 = a_dst2[16 + l16];
#pragma unroll
    for (int mi = 0; mi < 2; mi++)
#pragma unroll
        for (int j = 0; j < 4; j++) {
            int gr = row0 + wid * 32 + mi * 16 + l4 * 4 + j;
            float ps = acc[mi][0][j] * sa0 + acc[mi][1][j] * sa1;
            float pd = acc[mi][0][j] * da0 + acc[mi][1][j] * da1;
            ps += __shfl_xor(ps, 1); ps += __shfl_xor(ps, 2);
            ps += __shfl_xor(ps, 4); ps += __shfl_xor(ps, 8);
            pd += __shfl_xor(pd, 1); pd += __shfl_xor(pd, 2);
            pd += __shfl_xor(pd, 4); pd += __shfl_xor(pd, 8);
            if (l16 == 0 && gr < N) {
                as2[gr] = ps;
                ad2[gr] = pd;
            }
        }
}

// Layer-2 FUSED softmax + gather + bias + log_softmax (agg2f). [FROZEN R15]
__global__ __launch_bounds__(256) void agg2f_kernel(
        const float* __restrict__ h2,
        const float* __restrict__ as2, const float* __restrict__ ad2,
        const float* __restrict__ b2,
        const int* __restrict__ off, const int* __restrict__ esrc,
        float* __restrict__ out, int N) {
    __shared__ float s_w[8][32];        // 1 KB; [group][edge]
    int t = threadIdx.x;
    int g = t >> 5, c = t & 31;
    int node = blockIdx.x * 8 + g;
    if (node >= N) return;
    int beg = off[node], end = off[node + 1];
    int deg = end - beg;
    float adv = ad2[node];
    const float* hcol = h2 + c;
    float a0 = 0.f, a1 = 0.f, a2 = 0.f, a3 = 0.f;

    if (deg <= 32) {
        float e = -3.0e38f;
        if (c < deg) {
            float v = as2[esrc[beg + c]] + adv;
            e = (v > 0.f) ? v : 0.2f * v;   // leaky_relu(0.2)
        }
        float m = e;
#pragma unroll
        for (int s = 16; s > 0; s >>= 1) m = fmaxf(m, __shfl_xor(m, s, 32));
        float w = (c < deg) ? __expf(e - m) : 0.f;
        float dn = w;
#pragma unroll
        for (int s = 16; s > 0; s >>= 1) dn += __shfl_xor(dn, s, 32);
        s_w[g][c] = w * (1.f / (dn + 1e-16f));
        int j = beg;
        for (; j + 4 <= end; j += 4) {
            int k = j - beg;
            int s0 = esrc[j + 0], s1 = esrc[j + 1], s2 = esrc[j + 2], s3 = esrc[j + 3];
            float w0 = s_w[g][k + 0];
            float w1 = s_w[g][k + 1];
            float w2 = s_w[g][k + 2];
            float w3 = s_w[g][k + 3];
            a0 = fmaf(w0, hcol[(size_t)s0 * 32], a0);
            a1 = fmaf(w1, hcol[(size_t)s1 * 32], a1);
            a2 = fmaf(w2, hcol[(size_t)s2 * 32], a2);
            a3 = fmaf(w3, hcol[(size_t)s3 * 32], a3);
        }
        for (; j < end; j++)
            a0 = fmaf(s_w[g][j - beg], hcol[(size_t)esrc[j] * 32], a0);
    } else {
        float m = -3.0e38f, dnm = 0.f;
        for (int base = beg; base < end; base += 32) {
            int n_ch = min(32, end - base);
            float ej = -3.0e38f;
            if (c < n_ch) {
                float e = as2[esrc[base + c]] + adv;
                ej = (e > 0.f) ? e : 0.2f * e;
            }
            float cm = ej;
#pragma unroll
            for (int s = 16; s > 0; s >>= 1) cm = fmaxf(cm, __shfl_xor(cm, s, 32));
            float nm = fmaxf(m, cm);
            float scl = __expf(m - nm);
            float wj = (c < n_ch) ? __expf(ej - nm) : 0.f;
            float ws = wj;
#pragma unroll
            for (int s = 16; s > 0; s >>= 1) ws += __shfl_xor(ws, s, 32);
            dnm = dnm * scl + ws;
            m = nm;
        }
        float inv = 1.f / (dnm + 1e-16f);
        int j = beg;
        for (; j + 4 <= end; j += 4) {
            int s0 = esrc[j + 0], s1 = esrc[j + 1], s2 = esrc[j + 2], s3 = esrc[j + 3];
            float e0 = as2[s0] + adv, e1 = as2[s1] + adv;
            float e2 = as2[s2] + adv, e3 = as2[s3] + adv;
            e0 = (e0 > 0.f) ? e0 : 0.2f * e0;
            e1 = (e1 > 0.f) ? e1 : 0.2f * e1;
            e2 = (e2 > 0.f) ? e2 : 0.2f * e2;
            e3 = (e3 > 0.f) ? e3 : 0.2f * e3;
            float w0 = __expf(e0 - m) * inv, w1 = __expf(e1 - m) * inv;
            float w2 = __expf(e2 - m) * inv, w3 = __expf(e3 - m) * inv;
            a0 = fmaf(w0, hcol[(size_t)s0 * 32], a0);
            a1 = fmaf(w1, hcol[(size_t)s1 * 32], a1);
            a2 = fmaf(w2, hcol[(size_t)s2 * 32], a2);
            a3 = fmaf(w3, hcol[(size_t)s3 * 32], a3);
        }
        for (; j < end; j++) {
            int s0 = esrc[j];
            float e = as2[s0] + adv;
            e = (e > 0.f) ? e : 0.2f * e;
            a0 = fmaf(__expf(e - m) * inv, hcol[(size_t)s0 * 32], a0);
        }
    }

    float v = (a0 + a1) + (a2 + a3) + b2[c];
    float mx = v;
#pragma unroll
    for (int s = 16; s > 0; s >>= 1) mx = fmaxf(mx, __shfl_xor(mx, s, 32));
    float sum = __expf(v - mx);
#pragma unroll
    for (int s = 16; s > 0; s >>= 1) sum += __shfl_xor(sum, s, 32);
    out[(size_t)node * 32 + c] = (v - mx) - __logf(sum);
}

extern "C" void kernel_launch(void* const* d_in, const int* in_sizes, int n_in,
                              void* d_out, int out_size, void* d_ws, size_t ws_size,
                              hipStream_t stream) {
    const float* x      = (const float*)d_in[0];
    const void*  ei     = d_in[1];
    const float* W1     = (const float*)d_in[2];
    const float* a_src1 = (const float*)d_in[3];
    const float* a_dst1 = (const float*)d_in[4];
    const float* b1     = (const float*)d_in[5];
    const float* W2     = (const float*)d_in[6];
    const float* a_src2 = (const float*)d_in[7];
    const float* a_dst2 = (const float*)d_in[8];
    const float* b2     = (const float*)d_in[9];
    const int N  = in_sizes[0] / 256;   // 50000
    const int E  = in_sizes[1] / 2;     // 500000
    const int ET = E + N;
    float* outp = (float*)d_out;
    (void)n_in; (void)out_size; (void)ws_size;

    char* ws = (char*)d_ws;
    size_t o = 0;
    auto alloc = [&](size_t bytes) -> void* {
        void* p = ws + o;
        o += (bytes + 255) & ~(size_t)255;
        return p;
    };
    int*    flag   = (int*)alloc(4);
    int*    src32  = (int*)alloc((size_t)ET * 4);
    int*    dst32  = (int*)alloc((size_t)ET * 4);
    int*    deg    = (int*)alloc((size_t)2 * N * 4);  // deg + cursor, one memset
    int*    cursor = deg + N;
    int*    off    = (int*)alloc((size_t)(N + 1) * 4);
    int*    esrc   = (int*)alloc((size_t)ET * 4);
    int*    bsum   = (int*)alloc((size_t)1024 * 4);
    ushort* w1t    = (ushort*)alloc((size_t)256 * 256 * 2);
    ushort* w2t    = (ushort*)alloc((size_t)32 * 256 * 2);
    ushort* h1b    = (ushort*)alloc((size_t)N * 256 * 2);
    float*  as1    = (float*)alloc((size_t)N * 8 * 4);
    float*  ad1    = (float*)alloc((size_t)N * 8 * 4);
    ushort* hactb  = (ushort*)alloc((size_t)N * 256 * 2);
    float*  h2     = (float*)alloc((size_t)N * 32 * 4);
    float*  as2    = (float*)alloc((size_t)N * 4);
    float*  ad2    = (float*)alloc((size_t)N * 4);

    const int nbScan = (N + 255) / 256;   // 196

    hipMemsetAsync(deg, 0, (size_t)2 * N * 4, stream);
    detect_kernel<<<1, 256, 0, stream>>>((const int*)ei, flag);
    decode_degree_kernel<<<(ET + 255) / 256, 256, 0, stream>>>(ei, E, ET, N, flag,
                                                               src32, dst32, deg);
    scanA_kernel<<<nbScan, 256, 0, stream>>>(deg, bsum, N);
    scanB_kernel<<<1, 1024, 0, stream>>>(bsum, nbScan);
    scanC_kernel<<<nbScan, 256, 0, stream>>>(deg, bsum, off, N);
    scatter_kernel<<<(ET + 255) / 256, 256, 0, stream>>>(src32, dst32, ET, off,
                                                         cursor, esrc);

    convert_w_kernel<<<96, 256, 0, stream>>>(W1, W2, w1t, w2t);

    gemm1_mfma<<<dim3((N + 127) / 128, 2), 256, 0, stream>>>(x, w1t, a_src1, a_dst1,
                                                             h1b, as1, ad1, N);
    agg1f_kernel<<<(N + 7) / 8, 256, 0, stream>>>(h1b, as1, ad1, b1, off, esrc,
                                                  hactb, N);
    gemm2_mfma<<<(N + 127) / 128, 256, 0, stream>>>(hactb, w2t, a_src2, a_dst2,
                                                    h2, as2, ad2, N);
    agg2f_kernel<<<(N + 7) / 8, 256, 0, stream>>>(h2, as2, ad2, b2, off, esrc,
                                                  outp, N);
}

// Round 19
// 196.523 us; speedup vs baseline: 1.0867x; 1.0369x over previous
//
#include <hip/hip_runtime.h>
#include <math.h>

// ---------------------------------------------------------------------------
// GAT 2-layer forward (N=50000, F_in=256, H1=8, C1=32, C2=32, E=500000).
// R18: full revert to the R15 checkpoint (196.1 us) — the alpha-into-gemm
// epilogue fusion of R16/R17 regressed gemm1 (256 shfl/thread + acc liveness
// on a ramp-bound kernel; 54.2 us vs <50.8). Separate alpha1/alpha2 restored.
// agg1f (gather floor ~51us), agg2f, CSR chain, convert_w all frozen.
// ---------------------------------------------------------------------------

typedef __attribute__((ext_vector_type(8))) short bf16x8;
typedef __attribute__((ext_vector_type(4))) float f32x4;

__device__ __forceinline__ float bf2f(ushort u) {
    union { uint i; float f; } v; v.i = ((uint)u) << 16; return v.f;
}
__device__ __forceinline__ ushort f2bf(float f) {  // round-to-nearest-even
    union { float f; uint i; } v; v.f = f;
    uint r = v.i + 0x7FFFu + ((v.i >> 16) & 1u);
    return (ushort)(r >> 16);
}
__device__ __forceinline__ uint pack2(float a, float b) {
    return (uint)f2bf(a) | ((uint)f2bf(b) << 16);
}

// int64 little-endian values < 2^31 => every odd 32-bit word is 0.
__global__ void detect_kernel(const int* ei32, int* flag) {
    __shared__ int cnt;
    if (threadIdx.x == 0) cnt = 0;
    __syncthreads();
    int nz = 0;
    for (int i = threadIdx.x; i < 1024; i += blockDim.x)
        if (ei32[2 * i + 1] != 0) nz++;
    atomicAdd(&cnt, nz);
    __syncthreads();
    if (threadIdx.x == 0) *flag = (cnt > 16) ? 1 : 0;  // 1 => int32 layout
}

__global__ void decode_degree_kernel(const void* ei, int E, int ET, int N,
                                     const int* __restrict__ flag,
                                     int* __restrict__ src, int* __restrict__ dst,
                                     int* __restrict__ deg) {
    int k = blockIdx.x * blockDim.x + threadIdx.x;
    if (k >= ET) return;
    int s, d;
    if (k < E) {
        if (*flag) {
            const int* p = (const int*)ei;
            s = p[k]; d = p[E + k];
        } else {
            const long long* p = (const long long*)ei;
            s = (int)p[k]; d = (int)p[E + k];
        }
    } else {
        s = d = k - E;  // self-loops appended
    }
    s = min(max(s, 0), N - 1);
    d = min(max(d, 0), N - 1);
    src[k] = s; dst[k] = d;
    atomicAdd(&deg[d], 1);
}

// --- 3-phase hierarchical exclusive scan (coalesced, parallel) -------------
__global__ __launch_bounds__(256) void scanA_kernel(const int* __restrict__ deg,
                                                    int* __restrict__ bsum, int n) {
    int i = blockIdx.x * 256 + threadIdx.x;
    int v = (i < n) ? deg[i] : 0;
#pragma unroll
    for (int s = 1; s < 64; s <<= 1) v += __shfl_xor(v, s, 64);
    __shared__ int ws[4];
    int lane = threadIdx.x & 63, wid = threadIdx.x >> 6;
    if (lane == 0) ws[wid] = v;
    __syncthreads();
    if (threadIdx.x == 0) bsum[blockIdx.x] = ws[0] + ws[1] + ws[2] + ws[3];
}

__global__ __launch_bounds__(1024) void scanB_kernel(int* __restrict__ bsum, int nb) {
    int t = threadIdx.x;
    int v = (t < nb) ? bsum[t] : 0;
    __shared__ int sm[1024];
    sm[t] = v;
    __syncthreads();
    for (int s = 1; s < 1024; s <<= 1) {
        int a = (t >= s) ? sm[t - s] : 0;
        __syncthreads();
        sm[t] += a;
        __syncthreads();
    }
    if (t < nb) bsum[t] = sm[t] - v;  // exclusive
}

__global__ __launch_bounds__(256) void scanC_kernel(const int* __restrict__ deg,
                                                    const int* __restrict__ bsum,
                                                    int* __restrict__ off, int n) {
    int t = threadIdx.x;
    int i = blockIdx.x * 256 + t;
    int v = (i < n) ? deg[i] : 0;
    int incl = v;
    int lane = t & 63, wid = t >> 6;
#pragma unroll
    for (int s = 1; s < 64; s <<= 1) {
        int a = __shfl_up(incl, s, 64);
        if (lane >= s) incl += a;
    }
    __shared__ int wsum[4];
    if (lane == 63) wsum[wid] = incl;
    __syncthreads();
    int wo = 0;
    for (int w = 0; w < wid; w++) wo += wsum[w];
    if (i < n) off[i + 1] = bsum[blockIdx.x] + wo + incl;
    if (i == 0) off[0] = 0;
}

__global__ void scatter_kernel(const int* __restrict__ src, const int* __restrict__ dst,
                               int ET, const int* __restrict__ off,
                               int* __restrict__ cursor, int* __restrict__ esrc) {
    int k = blockIdx.x * blockDim.x + threadIdx.x;
    if (k >= ET) return;
    int d = dst[k];
    int p = atomicAdd(&cursor[d], 1);
    esrc[off[d] + p] = src[k];
}

// Merged weight conversion: blocks 0..63 transpose W1 -> w1t (32x32 LDS
// tiles); blocks 64..95 convert W2 -> w2t (transposed, c-major).
__global__ __launch_bounds__(256) void convert_w_kernel(
        const float* __restrict__ W1, const float* __restrict__ W2,
        ushort* __restrict__ w1t, ushort* __restrict__ w2t) {
    int bid = blockIdx.x;
    if (bid < 64) {
        __shared__ float tile[32][33];
        int tx = threadIdx.x & 31, ty = threadIdx.x >> 5;
        int bx = bid & 7, by = bid >> 3;
        for (int i = 0; i < 32; i += 8)
            tile[ty + i][tx] = W1[(by * 32 + ty + i) * 256 + bx * 32 + tx];
        __syncthreads();
        for (int i = 0; i < 32; i += 8)
            w1t[(bx * 32 + ty + i) * 256 + by * 32 + tx] = f2bf(tile[tx][ty + i]);
    } else {
        int idx = (bid - 64) * 256 + threadIdx.x;   // 32 blocks x 256 = 8192
        int c = idx >> 8, k = idx & 255;
        w2t[idx] = f2bf(W2[k * 32 + c]);
    }
}

// h1 = x @ W1 via bf16 MFMA. 128x128 tile, BK=64, 4 waves (2x2), 4x4 frags.
// A-staging reads x as f32 and converts to bf16 in-register (fused convert_x).
#define LDA 72
__global__ __launch_bounds__(256) void gemm1_mfma(
        const float* __restrict__ x,      // [N][256] f32
        const ushort* __restrict__ w1t,   // [256][256] bf16 (n-major)
        ushort* __restrict__ h1b,         // [N][256] bf16 out
        int N) {
    __shared__ ushort Al[128 * LDA];
    __shared__ ushort Bl[128 * LDA];
    int t = threadIdx.x;
    int row0 = blockIdx.x * 128;
    int n0 = blockIdx.y * 128;
    int lane = t & 63, wid = t >> 6;
    int wr = wid >> 1, wc = wid & 1;

    f32x4 acc[4][4] = {};

    int sr = t >> 1, scs = (t & 1) * 32;
    for (int k0 = 0; k0 < 256; k0 += 64) {
        // stage A tile (128 x 64) f32 -> bf16
        {
            int gr = row0 + sr;
            float4 f[8];
            if (gr < N) {
                const float4* g = (const float4*)(x + (size_t)gr * 256 + k0 + scs);
#pragma unroll
                for (int q = 0; q < 8; q++) f[q] = g[q];
            } else {
#pragma unroll
                for (int q = 0; q < 8; q++) f[q] = float4{0.f, 0.f, 0.f, 0.f};
            }
            uint4* d = (uint4*)&Al[sr * LDA + scs];
#pragma unroll
            for (int p = 0; p < 4; p++) {
                uint4 u;
                u.x = pack2(f[2 * p].x, f[2 * p].y);
                u.y = pack2(f[2 * p].z, f[2 * p].w);
                u.z = pack2(f[2 * p + 1].x, f[2 * p + 1].y);
                u.w = pack2(f[2 * p + 1].z, f[2 * p + 1].w);
                d[p] = u;
            }
        }
        // stage B tile (128 n-rows x 64 k) from pre-transposed w1t
        {
            const uint4* g = (const uint4*)(w1t + (size_t)(n0 + sr) * 256 + k0 + scs);
            uint4* d = (uint4*)&Bl[sr * LDA + scs];
            d[0] = g[0]; d[1] = g[1]; d[2] = g[2]; d[3] = g[3];
        }
        __syncthreads();

#pragma unroll
        for (int ks = 0; ks < 2; ks++) {
            int kk = ks * 32 + (lane >> 4) * 8;
            bf16x8 af[4], bfr[4];
#pragma unroll
            for (int mi = 0; mi < 4; mi++) {
                int r = wr * 64 + mi * 16 + (lane & 15);
                af[mi] = *(const bf16x8*)&Al[r * LDA + kk];
            }
#pragma unroll
            for (int ni = 0; ni < 4; ni++) {
                int r = wc * 64 + ni * 16 + (lane & 15);
                bfr[ni] = *(const bf16x8*)&Bl[r * LDA + kk];
            }
#pragma unroll
            for (int mi = 0; mi < 4; mi++)
#pragma unroll
                for (int ni = 0; ni < 4; ni++)
                    acc[mi][ni] = __builtin_amdgcn_mfma_f32_16x16x32_bf16(
                        af[mi], bfr[ni], acc[mi][ni], 0, 0, 0);
        }
        __syncthreads();
    }

    // C/D layout (m89/m91): col = lane&15, row = (lane>>4)*4 + j
#pragma unroll
    for (int mi = 0; mi < 4; mi++)
#pragma unroll
        for (int ni = 0; ni < 4; ni++) {
            int gc = n0 + wc * 64 + ni * 16 + (lane & 15);
#pragma unroll
            for (int j = 0; j < 4; j++) {
                int gr = row0 + wr * 64 + mi * 16 + (lane >> 4) * 4 + j;
                if (gr < N) h1b[(size_t)gr * 256 + gc] = f2bf(acc[mi][ni][j]);
            }
        }
}

// as1/ad1 per (node, head) from bf16 h1. 32-lane group per node.
__global__ __launch_bounds__(256) void alpha1_kernel(
        const ushort* __restrict__ h1b,
        const float* __restrict__ a_src1, const float* __restrict__ a_dst1,
        float* __restrict__ as1, float* __restrict__ ad1, int N) {
    int t = threadIdx.x;
    int g = t >> 5, l = t & 31;
    int node = blockIdx.x * 8 + g;
    if (node >= N) return;
    bf16x8 hv = *(const bf16x8*)&h1b[(size_t)node * 256 + l * 8];
    float s = 0.f, d = 0.f;
#pragma unroll
    for (int i = 0; i < 8; i++) {
        float h = bf2f((ushort)hv[i]);
        s = fmaf(h, a_src1[l * 8 + i], s);
        d = fmaf(h, a_dst1[l * 8 + i], d);
    }
    s += __shfl_xor(s, 1); s += __shfl_xor(s, 2);
    d += __shfl_xor(d, 1); d += __shfl_xor(d, 2);
    if ((l & 3) == 0) {
        as1[node * 8 + (l >> 2)] = s;
        ad1[node * 8 + (l >> 2)] = d;
    }
}

// Layer-1 FUSED softmax + gather (agg1f). TWO nodes per wave: each 32-lane
// half owns one node, 8 channels/lane via uint4. Phase 1 = single as1 pass ->
// shfl stats -> LDS weights (half-wave private, no barriers). Phase 2 =
// simple 4-wide+tail gather. [FROZEN from R13]
#define FMA8(W, V)                                                      \
    c0 = fmaf(W, bf2f((ushort)((V).x & 0xffffu)), c0);                  \
    c1 = fmaf(W, bf2f((ushort)((V).x >> 16)), c1);                      \
    c2 = fmaf(W, bf2f((ushort)((V).y & 0xffffu)), c2);                  \
    c3 = fmaf(W, bf2f((ushort)((V).y >> 16)), c3);                      \
    c4 = fmaf(W, bf2f((ushort)((V).z & 0xffffu)), c4);                  \
    c5 = fmaf(W, bf2f((ushort)((V).z >> 16)), c5);                      \
    c6 = fmaf(W, bf2f((ushort)((V).w & 0xffffu)), c6);                  \
    c7 = fmaf(W, bf2f((ushort)((V).w >> 16)), c7);

__global__ __launch_bounds__(256) void agg1f_kernel(
        const ushort* __restrict__ h1b,
        const float* __restrict__ as1, const float* __restrict__ ad1,
        const float* __restrict__ b1,
        const int* __restrict__ off, const int* __restrict__ esrc,
        ushort* __restrict__ hactb, int N) {
    __shared__ float s_w[8][32][8];     // 8 KB; [node-slot][edge][head]
    int t = threadIdx.x;
    int slot = t >> 5;                  // node slot 0..7 (2 per wave)
    int node = blockIdx.x * 8 + slot;
    int l = t & 31;                     // lane within half-wave
    if (node >= N) return;
    int beg = off[node], end = off[node + 1];
    int deg = end - beg;
    int h = l & 7, q = l >> 3;          // phase-1 role: edge-slot q (0..3), head h
    float adv = ad1[node * 8 + h];
    int head2 = l >> 2;                 // phase-2 role: 8 ch/lane, head = ch0/32
    int ch0 = l * 8;
    const ushort* hb = h1b + ch0;
    float c0 = 0.f, c1 = 0.f, c2 = 0.f, c3 = 0.f;
    float c4 = 0.f, c5 = 0.f, c6 = 0.f, c7 = 0.f;

    if (deg <= 32) {
        float e_r[8];
#pragma unroll
        for (int r = 0; r < 8; r++) {
            int j = beg + r * 4 + q;
            float e = -3.0e38f;
            if (j < end) {
                e = as1[esrc[j] * 8 + h] + adv;
                e = (e > 0.f) ? e : 0.2f * e;   // leaky_relu(0.2)
            }
            e_r[r] = e;
        }
        float m = e_r[0];
#pragma unroll
        for (int r = 1; r < 8; r++) m = fmaxf(m, e_r[r]);
        m = fmaxf(m, __shfl_xor(m, 8, 32));
        m = fmaxf(m, __shfl_xor(m, 16, 32));
        float dnm = 0.f;
#pragma unroll
        for (int r = 0; r < 8; r++)
            if (beg + r * 4 + q < end) dnm += __expf(e_r[r] - m);
        dnm += __shfl_xor(dnm, 8, 32);
        dnm += __shfl_xor(dnm, 16, 32);
        float inv = 1.f / (dnm + 1e-16f);
#pragma unroll
        for (int r = 0; r < 8; r++) {
            int j = beg + r * 4 + q;
            if (j < end) s_w[slot][r * 4 + q][h] = __expf(e_r[r] - m) * inv;
        }
        const float* wp = &s_w[slot][0][head2];
        int j = beg;
        for (; j + 4 <= end; j += 4) {
            int k = j - beg;
            int s0 = esrc[j + 0], s1 = esrc[j + 1], s2 = esrc[j + 2], s3 = esrc[j + 3];
            float w0 = wp[(k + 0) * 8];
            float w1 = wp[(k + 1) * 8];
            float w2 = wp[(k + 2) * 8];
            float w3 = wp[(k + 3) * 8];
            uint4 v0 = *(const uint4*)(hb + (size_t)s0 * 256);
            uint4 v1 = *(const uint4*)(hb + (size_t)s1 * 256);
            uint4 v2 = *(const uint4*)(hb + (size_t)s2 * 256);
            uint4 v3 = *(const uint4*)(hb + (size_t)s3 * 256);
            FMA8(w0, v0);
            FMA8(w1, v1);
            FMA8(w2, v2);
            FMA8(w3, v3);
        }
        for (; j < end; j++) {
            int s0 = esrc[j];
            float w = wp[(j - beg) * 8];
            uint4 v = *(const uint4*)(hb + (size_t)s0 * 256);
            FMA8(w, v);
        }
    } else {
        float m = -3.0e38f;
        for (int j0 = beg; j0 < end; j0 += 4) {
            int j = j0 + q;
            if (j < end) {
                float e = as1[esrc[j] * 8 + h] + adv;
                e = (e > 0.f) ? e : 0.2f * e;
                m = fmaxf(m, e);
            }
        }
        m = fmaxf(m, __shfl_xor(m, 8, 32));
        m = fmaxf(m, __shfl_xor(m, 16, 32));
        float dnm = 0.f;
        for (int j0 = beg; j0 < end; j0 += 4) {
            int j = j0 + q;
            if (j < end) {
                float e = as1[esrc[j] * 8 + h] + adv;
                e = (e > 0.f) ? e : 0.2f * e;
                dnm += __expf(e - m);
            }
        }
        dnm += __shfl_xor(dnm, 8, 32);
        dnm += __shfl_xor(dnm, 16, 32);
        float inv = 1.f / (dnm + 1e-16f);
        float m2   = __shfl(m, head2, 32);
        float inv2 = __shfl(inv, head2, 32);
        float adv2 = __shfl(adv, head2, 32);
        const float* asp = as1 + head2;
        for (int j = beg; j < end; j++) {
            int s0 = esrc[j];
            float e = asp[s0 * 8] + adv2;
            e = (e > 0.f) ? e : 0.2f * e;
            float w = __expf(e - m2) * inv2;
            uint4 v = *(const uint4*)(hb + (size_t)s0 * 256);
            FMA8(w, v);
        }
    }

    float4 bv0 = *(const float4*)&b1[ch0];
    float4 bv1 = *(const float4*)&b1[ch0 + 4];
    float o0 = c0 + bv0.x, o1 = c1 + bv0.y, o2 = c2 + bv0.z, o3 = c3 + bv0.w;
    float o4 = c4 + bv1.x, o5 = c5 + bv1.y, o6 = c6 + bv1.z, o7 = c7 + bv1.w;
    o0 = (o0 > 0.f) ? o0 : (__expf(o0) - 1.f);
    o1 = (o1 > 0.f) ? o1 : (__expf(o1) - 1.f);
    o2 = (o2 > 0.f) ? o2 : (__expf(o2) - 1.f);
    o3 = (o3 > 0.f) ? o3 : (__expf(o3) - 1.f);
    o4 = (o4 > 0.f) ? o4 : (__expf(o4) - 1.f);
    o5 = (o5 > 0.f) ? o5 : (__expf(o5) - 1.f);
    o6 = (o6 > 0.f) ? o6 : (__expf(o6) - 1.f);
    o7 = (o7 > 0.f) ? o7 : (__expf(o7) - 1.f);
    uint4 r;
    r.x = pack2(o0, o1);
    r.y = pack2(o2, o3);
    r.z = pack2(o4, o5);
    r.w = pack2(o6, o7);
    *(uint4*)(hactb + (size_t)node * 256 + ch0) = r;
}

// h2 = hactb @ W2 via bf16 MFMA. Tile 128x32, BK=64, 4 waves each owning a
// 32x32 m-subtile (2x2 frags). Output f32.
__global__ __launch_bounds__(256) void gemm2_mfma(
        const ushort* __restrict__ hactb,  // [N][256] bf16
        const ushort* __restrict__ w2t,    // [32][256] bf16 (c-major)
        float* __restrict__ h2, int N) {
    __shared__ ushort Al[128 * LDA];
    __shared__ ushort Bl[32 * LDA];
    int t = threadIdx.x;
    int row0 = blockIdx.x * 128;
    int lane = t & 63, wid = t >> 6;

    f32x4 acc[2][2] = {};

    int sr = t >> 1, scs = (t & 1) * 32;
    for (int k0 = 0; k0 < 256; k0 += 64) {
        {
            int gr = row0 + sr;
            uint4 v0 = {0,0,0,0}, v1 = {0,0,0,0}, v2 = {0,0,0,0}, v3 = {0,0,0,0};
            if (gr < N) {
                const uint4* g = (const uint4*)(hactb + (size_t)gr * 256 + k0 + scs);
                v0 = g[0]; v1 = g[1]; v2 = g[2]; v3 = g[3];
            }
            uint4* d = (uint4*)&Al[sr * LDA + scs];
            d[0] = v0; d[1] = v1; d[2] = v2; d[3] = v3;
        }
        if (t < 64) {
            const uint4* g = (const uint4*)(w2t + (size_t)sr * 256 + k0 + scs);
            uint4* d = (uint4*)&Bl[sr * LDA + scs];
            d[0] = g[0]; d[1] = g[1]; d[2] = g[2]; d[3] = g[3];
        }
        __syncthreads();

#pragma unroll
        for (int ks = 0; ks < 2; ks++) {
            int kk = ks * 32 + (lane >> 4) * 8;
            bf16x8 af[2], bfr[2];
#pragma unroll
            for (int mi = 0; mi < 2; mi++) {
                int r = wid * 32 + mi * 16 + (lane & 15);
                af[mi] = *(const bf16x8*)&Al[r * LDA + kk];
            }
#pragma unroll
            for (int ni = 0; ni < 2; ni++) {
                int r = ni * 16 + (lane & 15);
                bfr[ni] = *(const bf16x8*)&Bl[r * LDA + kk];
            }
#pragma unroll
            for (int mi = 0; mi < 2; mi++)
#pragma unroll
                for (int ni = 0; ni < 2; ni++)
                    acc[mi][ni] = __builtin_amdgcn_mfma_f32_16x16x32_bf16(
                        af[mi], bfr[ni], acc[mi][ni], 0, 0, 0);
        }
        __syncthreads();
    }

#pragma unroll
    for (int mi = 0; mi < 2; mi++)
#pragma unroll
        for (int ni = 0; ni < 2; ni++) {
            int gc = ni * 16 + (lane & 15);
#pragma unroll
            for (int j = 0; j < 4; j++) {
                int gr = row0 + wid * 32 + mi * 16 + (lane >> 4) * 4 + j;
                if (gr < N) h2[(size_t)gr * 32 + gc] = acc[mi][ni][j];
            }
        }
}

// as2/ad2 from h2: 8-lane group per node, float4 loads.
__global__ __launch_bounds__(256) void alpha2_kernel(
        const float* __restrict__ h2,
        const float* __restrict__ a_src2, const float* __restrict__ a_dst2,
        float* __restrict__ as2, float* __restrict__ ad2, int N) {
    int t = threadIdx.x;
    int g = t >> 3, q = t & 7;
    int node = blockIdx.x * 32 + g;
    if (node >= N) return;
    float4 v = *(const float4*)&h2[(size_t)node * 32 + q * 4];
    float4 sa = *(const float4*)&a_src2[q * 4];
    float4 da = *(const float4*)&a_dst2[q * 4];
    float s = v.x * sa.x + v.y * sa.y + v.z * sa.z + v.w * sa.w;
    float d = v.x * da.x + v.y * da.y + v.z * da.z + v.w * da.w;
    s += __shfl_xor(s, 1, 8); s += __shfl_xor(s, 2, 8); s += __shfl_xor(s, 4, 8);
    d += __shfl_xor(d, 1, 8); d += __shfl_xor(d, 2, 8); d += __shfl_xor(d, 4, 8);
    if (q == 0) { as2[node] = s; ad2[node] = d; }
}

// Layer-2 FUSED softmax + gather + bias + log_softmax (agg2f). 32-lane group
// per node (8/block). Fast path deg<=32: lane j owns edge j -> one as2 pass,
// exact shfl max/sum, normalized weights into group-private LDS (no barrier);
// gather reads weights via broadcast ds_read. deg>32: exact chunked fallback.
__global__ __launch_bounds__(256) void agg2f_kernel(
        const float* __restrict__ h2,
        const float* __restrict__ as2, const float* __restrict__ ad2,
        const float* __restrict__ b2,
        const int* __restrict__ off, const int* __restrict__ esrc,
        float* __restrict__ out, int N) {
    __shared__ float s_w[8][32];        // 1 KB; [group][edge]
    int t = threadIdx.x;
    int g = t >> 5, c = t & 31;
    int node = blockIdx.x * 8 + g;
    if (node >= N) return;
    int beg = off[node], end = off[node + 1];
    int deg = end - beg;
    float adv = ad2[node];
    const float* hcol = h2 + c;
    float a0 = 0.f, a1 = 0.f, a2 = 0.f, a3 = 0.f;

    if (deg <= 32) {
        float e = -3.0e38f;
        if (c < deg) {
            float v = as2[esrc[beg + c]] + adv;
            e = (v > 0.f) ? v : 0.2f * v;   // leaky_relu(0.2)
        }
        float m = e;
#pragma unroll
        for (int s = 16; s > 0; s >>= 1) m = fmaxf(m, __shfl_xor(m, s, 32));
        float w = (c < deg) ? __expf(e - m) : 0.f;
        float dn = w;
#pragma unroll
        for (int s = 16; s > 0; s >>= 1) dn += __shfl_xor(dn, s, 32);
        s_w[g][c] = w * (1.f / (dn + 1e-16f));
        int j = beg;
        for (; j + 4 <= end; j += 4) {
            int k = j - beg;
            int s0 = esrc[j + 0], s1 = esrc[j + 1], s2 = esrc[j + 2], s3 = esrc[j + 3];
            float w0 = s_w[g][k + 0];
            float w1 = s_w[g][k + 1];
            float w2 = s_w[g][k + 2];
            float w3 = s_w[g][k + 3];
            a0 = fmaf(w0, hcol[(size_t)s0 * 32], a0);
            a1 = fmaf(w1, hcol[(size_t)s1 * 32], a1);
            a2 = fmaf(w2, hcol[(size_t)s2 * 32], a2);
            a3 = fmaf(w3, hcol[(size_t)s3 * 32], a3);
        }
        for (; j < end; j++)
            a0 = fmaf(s_w[g][j - beg], hcol[(size_t)esrc[j] * 32], a0);
    } else {
        float m = -3.0e38f, dnm = 0.f;
        for (int base = beg; base < end; base += 32) {
            int n_ch = min(32, end - base);
            float ej = -3.0e38f;
            if (c < n_ch) {
                float e = as2[esrc[base + c]] + adv;
                ej = (e > 0.f) ? e : 0.2f * e;
            }
            float cm = ej;
#pragma unroll
            for (int s = 16; s > 0; s >>= 1) cm = fmaxf(cm, __shfl_xor(cm, s, 32));
            float nm = fmaxf(m, cm);
            float scl = __expf(m - nm);
            float wj = (c < n_ch) ? __expf(ej - nm) : 0.f;
            float ws = wj;
#pragma unroll
            for (int s = 16; s > 0; s >>= 1) ws += __shfl_xor(ws, s, 32);
            dnm = dnm * scl + ws;
            m = nm;
        }
        float inv = 1.f / (dnm + 1e-16f);
        int j = beg;
        for (; j + 4 <= end; j += 4) {
            int s0 = esrc[j + 0], s1 = esrc[j + 1], s2 = esrc[j + 2], s3 = esrc[j + 3];
            float e0 = as2[s0] + adv, e1 = as2[s1] + adv;
            float e2 = as2[s2] + adv, e3 = as2[s3] + adv;
            e0 = (e0 > 0.f) ? e0 : 0.2f * e0;
            e1 = (e1 > 0.f) ? e1 : 0.2f * e1;
            e2 = (e2 > 0.f) ? e2 : 0.2f * e2;
            e3 = (e3 > 0.f) ? e3 : 0.2f * e3;
            float w0 = __expf(e0 - m) * inv, w1 = __expf(e1 - m) * inv;
            float w2 = __expf(e2 - m) * inv, w3 = __expf(e3 - m) * inv;
            a0 = fmaf(w0, hcol[(size_t)s0 * 32], a0);
            a1 = fmaf(w1, hcol[(size_t)s1 * 32], a1);
            a2 = fmaf(w2, hcol[(size_t)s2 * 32], a2);
            a3 = fmaf(w3, hcol[(size_t)s3 * 32], a3);
        }
        for (; j < end; j++) {
            int s0 = esrc[j];
            float e = as2[s0] + adv;
            e = (e > 0.f) ? e : 0.2f * e;
            a0 = fmaf(__expf(e - m) * inv, hcol[(size_t)s0 * 32], a0);
        }
    }

    float v = (a0 + a1) + (a2 + a3) + b2[c];
    float mx = v;
#pragma unroll
    for (int s = 16; s > 0; s >>= 1) mx = fmaxf(mx, __shfl_xor(mx, s, 32));
    float sum = __expf(v - mx);
#pragma unroll
    for (int s = 16; s > 0; s >>= 1) sum += __shfl_xor(sum, s, 32);
    out[(size_t)node * 32 + c] = (v - mx) - __logf(sum);
}

extern "C" void kernel_launch(void* const* d_in, const int* in_sizes, int n_in,
                              void* d_out, int out_size, void* d_ws, size_t ws_size,
                              hipStream_t stream) {
    const float* x      = (const float*)d_in[0];
    const void*  ei     = d_in[1];
    const float* W1     = (const float*)d_in[2];
    const float* a_src1 = (const float*)d_in[3];
    const float* a_dst1 = (const float*)d_in[4];
    const float* b1     = (const float*)d_in[5];
    const float* W2     = (const float*)d_in[6];
    const float* a_src2 = (const float*)d_in[7];
    const float* a_dst2 = (const float*)d_in[8];
    const float* b2     = (const float*)d_in[9];
    const int N  = in_sizes[0] / 256;   // 50000
    const int E  = in_sizes[1] / 2;     // 500000
    const int ET = E + N;
    float* outp = (float*)d_out;
    (void)n_in; (void)out_size; (void)ws_size;

    char* ws = (char*)d_ws;
    size_t o = 0;
    auto alloc = [&](size_t bytes) -> void* {
        void* p = ws + o;
        o += (bytes + 255) & ~(size_t)255;
        return p;
    };
    int*    flag   = (int*)alloc(4);
    int*    src32  = (int*)alloc((size_t)ET * 4);
    int*    dst32  = (int*)alloc((size_t)ET * 4);
    int*    deg    = (int*)alloc((size_t)2 * N * 4);  // deg + cursor, one memset
    int*    cursor = deg + N;
    int*    off    = (int*)alloc((size_t)(N + 1) * 4);
    int*    esrc   = (int*)alloc((size_t)ET * 4);
    int*    bsum   = (int*)alloc((size_t)1024 * 4);
    ushort* w1t    = (ushort*)alloc((size_t)256 * 256 * 2);
    ushort* w2t    = (ushort*)alloc((size_t)32 * 256 * 2);
    ushort* h1b    = (ushort*)alloc((size_t)N * 256 * 2);
    float*  as1    = (float*)alloc((size_t)N * 8 * 4);
    float*  ad1    = (float*)alloc((size_t)N * 8 * 4);
    ushort* hactb  = (ushort*)alloc((size_t)N * 256 * 2);
    float*  h2     = (float*)alloc((size_t)N * 32 * 4);
    float*  as2    = (float*)alloc((size_t)N * 4);
    float*  ad2    = (float*)alloc((size_t)N * 4);

    const int nbScan = (N + 255) / 256;   // 196

    hipMemsetAsync(deg, 0, (size_t)2 * N * 4, stream);
    detect_kernel<<<1, 256, 0, stream>>>((const int*)ei, flag);
    decode_degree_kernel<<<(ET + 255) / 256, 256, 0, stream>>>(ei, E, ET, N, flag,
                                                               src32, dst32, deg);
    scanA_kernel<<<nbScan, 256, 0, stream>>>(deg, bsum, N);
    scanB_kernel<<<1, 1024, 0, stream>>>(bsum, nbScan);
    scanC_kernel<<<nbScan, 256, 0, stream>>>(deg, bsum, off, N);
    scatter_kernel<<<(ET + 255) / 256, 256, 0, stream>>>(src32, dst32, ET, off,
                                                         cursor, esrc);

    convert_w_kernel<<<96, 256, 0, stream>>>(W1, W2, w1t, w2t);

    gemm1_mfma<<<dim3((N + 127) / 128, 2), 256, 0, stream>>>(x, w1t, h1b, N);
    alpha1_kernel<<<(N + 7) / 8, 256, 0, stream>>>(h1b, a_src1, a_dst1, as1, ad1, N);
    agg1f_kernel<<<(N + 7) / 8, 256, 0, stream>>>(h1b, as1, ad1, b1, off, esrc,
                                                  hactb, N);
    gemm2_mfma<<<(N + 127) / 128, 256, 0, stream>>>(hactb, w2t, h2, N);
    alpha2_kernel<<<(N + 31) / 32, 256, 0, stream>>>(h2, a_src2, a_dst2, as2, ad2, N);
    agg2f_kernel<<<(N + 7) / 8, 256, 0, stream>>>(h2, as2, ad2, b2, off, esrc,
                                                  outp, N);
}

// Round 20
// 195.217 us; speedup vs baseline: 1.0940x; 1.0067x over previous
//
#include <hip/hip_runtime.h>
#include <math.h>

// ---------------------------------------------------------------------------
// GAT 2-layer forward (N=50000, F_in=256, H1=8, C1=32, C2=32, E=500000).
// R19: launch-chain slimming — (1) int64/int32 layout detection folded into
// decode_degree (per-block redundant count of first 1024 odd words; removes
// detect dispatch + flag round-trip); (2) scanB folded into scanC (per-block
// redundant 256-wide LDS scan of block sums; removes the 1-block dispatch).
// All compute kernels byte-identical to the R15/R18 checkpoint (196 us):
// gemm1/gemm2 MFMA, alpha1/alpha2, agg1f (gather floor ~51us), agg2f.
// ---------------------------------------------------------------------------

typedef __attribute__((ext_vector_type(8))) short bf16x8;
typedef __attribute__((ext_vector_type(4))) float f32x4;

__device__ __forceinline__ float bf2f(ushort u) {
    union { uint i; float f; } v; v.i = ((uint)u) << 16; return v.f;
}
__device__ __forceinline__ ushort f2bf(float f) {  // round-to-nearest-even
    union { float f; uint i; } v; v.f = f;
    uint r = v.i + 0x7FFFu + ((v.i >> 16) & 1u);
    return (ushort)(r >> 16);
}
__device__ __forceinline__ uint pack2(float a, float b) {
    return (uint)f2bf(a) | ((uint)f2bf(b) << 16);
}

// Decode edges (+ self-loops) and count in-degree. Layout detection is done
// per-block (redundantly): int64 little-endian values < 2^31 have every odd
// 32-bit word zero; the probe words are L2-hot after the first block.
__global__ void decode_degree_kernel(const void* ei, int E, int ET, int N,
                                     int* __restrict__ src, int* __restrict__ dst,
                                     int* __restrict__ deg) {
    __shared__ int cnt;
    if (threadIdx.x == 0) cnt = 0;
    __syncthreads();
    const int* p32 = (const int*)ei;
    int nz = 0;
    for (int i = threadIdx.x; i < 1024; i += blockDim.x)
        if (p32[2 * i + 1] != 0) nz++;
    if (nz) atomicAdd(&cnt, nz);
    __syncthreads();
    bool is32 = (cnt > 16);             // 1 => int32 layout

    int k = blockIdx.x * blockDim.x + threadIdx.x;
    if (k >= ET) return;
    int s, d;
    if (k < E) {
        if (is32) {
            s = p32[k]; d = p32[E + k];
        } else {
            const long long* p = (const long long*)ei;
            s = (int)p[k]; d = (int)p[E + k];
        }
    } else {
        s = d = k - E;  // self-loops appended
    }
    s = min(max(s, 0), N - 1);
    d = min(max(d, 0), N - 1);
    src[k] = s; dst[k] = d;
    atomicAdd(&deg[d], 1);
}

// --- 2-phase hierarchical exclusive scan (coalesced, parallel) -------------
// Phase A: per-block (256-elem chunk) sums.
__global__ __launch_bounds__(256) void scanA_kernel(const int* __restrict__ deg,
                                                    int* __restrict__ bsum, int n) {
    int i = blockIdx.x * 256 + threadIdx.x;
    int v = (i < n) ? deg[i] : 0;
#pragma unroll
    for (int s = 1; s < 64; s <<= 1) v += __shfl_xor(v, s, 64);
    __shared__ int ws[4];
    int lane = threadIdx.x & 63, wid = threadIdx.x >> 6;
    if (lane == 0) ws[wid] = v;
    __syncthreads();
    if (threadIdx.x == 0) bsum[blockIdx.x] = ws[0] + ws[1] + ws[2] + ws[3];
}

// Phase C (fused former scanB): each block redundantly scans the <=256 block
// sums in LDS to get its own exclusive base, then does its per-block
// inclusive scan of deg and writes off[i+1]; off[0]=0.
__global__ __launch_bounds__(256) void scanC_kernel(const int* __restrict__ deg,
                                                    const int* __restrict__ bsum,
                                                    int* __restrict__ off,
                                                    int n, int nb) {
    __shared__ int sb[256];
    int t = threadIdx.x;
    sb[t] = (t < nb) ? bsum[t] : 0;
    __syncthreads();
    for (int s = 1; s < 256; s <<= 1) {
        int a = (t >= s) ? sb[t - s] : 0;
        __syncthreads();
        sb[t] += a;
        __syncthreads();
    }
    int base = (blockIdx.x == 0) ? 0 : sb[blockIdx.x - 1];

    int i = blockIdx.x * 256 + t;
    int v = (i < n) ? deg[i] : 0;
    int incl = v;
    int lane = t & 63, wid = t >> 6;
#pragma unroll
    for (int s = 1; s < 64; s <<= 1) {
        int a = __shfl_up(incl, s, 64);
        if (lane >= s) incl += a;
    }
    __shared__ int wsum[4];
    if (lane == 63) wsum[wid] = incl;
    __syncthreads();
    int wo = 0;
    for (int w = 0; w < wid; w++) wo += wsum[w];
    if (i < n) off[i + 1] = base + wo + incl;
    if (i == 0) off[0] = 0;
}

__global__ void scatter_kernel(const int* __restrict__ src, const int* __restrict__ dst,
                               int ET, const int* __restrict__ off,
                               int* __restrict__ cursor, int* __restrict__ esrc) {
    int k = blockIdx.x * blockDim.x + threadIdx.x;
    if (k >= ET) return;
    int d = dst[k];
    int p = atomicAdd(&cursor[d], 1);
    esrc[off[d] + p] = src[k];
}

// Merged weight conversion: blocks 0..63 transpose W1 -> w1t (32x32 LDS
// tiles); blocks 64..95 convert W2 -> w2t (transposed, c-major).
__global__ __launch_bounds__(256) void convert_w_kernel(
        const float* __restrict__ W1, const float* __restrict__ W2,
        ushort* __restrict__ w1t, ushort* __restrict__ w2t) {
    int bid = blockIdx.x;
    if (bid < 64) {
        __shared__ float tile[32][33];
        int tx = threadIdx.x & 31, ty = threadIdx.x >> 5;
        int bx = bid & 7, by = bid >> 3;
        for (int i = 0; i < 32; i += 8)
            tile[ty + i][tx] = W1[(by * 32 + ty + i) * 256 + bx * 32 + tx];
        __syncthreads();
        for (int i = 0; i < 32; i += 8)
            w1t[(bx * 32 + ty + i) * 256 + by * 32 + tx] = f2bf(tile[tx][ty + i]);
    } else {
        int idx = (bid - 64) * 256 + threadIdx.x;   // 32 blocks x 256 = 8192
        int c = idx >> 8, k = idx & 255;
        w2t[idx] = f2bf(W2[k * 32 + c]);
    }
}

// h1 = x @ W1 via bf16 MFMA. 128x128 tile, BK=64, 4 waves (2x2), 4x4 frags.
// A-staging reads x as f32 and converts to bf16 in-register. [FROZEN]
#define LDA 72
__global__ __launch_bounds__(256) void gemm1_mfma(
        const float* __restrict__ x,      // [N][256] f32
        const ushort* __restrict__ w1t,   // [256][256] bf16 (n-major)
        ushort* __restrict__ h1b,         // [N][256] bf16 out
        int N) {
    __shared__ ushort Al[128 * LDA];
    __shared__ ushort Bl[128 * LDA];
    int t = threadIdx.x;
    int row0 = blockIdx.x * 128;
    int n0 = blockIdx.y * 128;
    int lane = t & 63, wid = t >> 6;
    int wr = wid >> 1, wc = wid & 1;

    f32x4 acc[4][4] = {};

    int sr = t >> 1, scs = (t & 1) * 32;
    for (int k0 = 0; k0 < 256; k0 += 64) {
        {
            int gr = row0 + sr;
            float4 f[8];
            if (gr < N) {
                const float4* g = (const float4*)(x + (size_t)gr * 256 + k0 + scs);
#pragma unroll
                for (int q = 0; q < 8; q++) f[q] = g[q];
            } else {
#pragma unroll
                for (int q = 0; q < 8; q++) f[q] = float4{0.f, 0.f, 0.f, 0.f};
            }
            uint4* d = (uint4*)&Al[sr * LDA + scs];
#pragma unroll
            for (int p = 0; p < 4; p++) {
                uint4 u;
                u.x = pack2(f[2 * p].x, f[2 * p].y);
                u.y = pack2(f[2 * p].z, f[2 * p].w);
                u.z = pack2(f[2 * p + 1].x, f[2 * p + 1].y);
                u.w = pack2(f[2 * p + 1].z, f[2 * p + 1].w);
                d[p] = u;
            }
        }
        {
            const uint4* g = (const uint4*)(w1t + (size_t)(n0 + sr) * 256 + k0 + scs);
            uint4* d = (uint4*)&Bl[sr * LDA + scs];
            d[0] = g[0]; d[1] = g[1]; d[2] = g[2]; d[3] = g[3];
        }
        __syncthreads();

#pragma unroll
        for (int ks = 0; ks < 2; ks++) {
            int kk = ks * 32 + (lane >> 4) * 8;
            bf16x8 af[4], bfr[4];
#pragma unroll
            for (int mi = 0; mi < 4; mi++) {
                int r = wr * 64 + mi * 16 + (lane & 15);
                af[mi] = *(const bf16x8*)&Al[r * LDA + kk];
            }
#pragma unroll
            for (int ni = 0; ni < 4; ni++) {
                int r = wc * 64 + ni * 16 + (lane & 15);
                bfr[ni] = *(const bf16x8*)&Bl[r * LDA + kk];
            }
#pragma unroll
            for (int mi = 0; mi < 4; mi++)
#pragma unroll
                for (int ni = 0; ni < 4; ni++)
                    acc[mi][ni] = __builtin_amdgcn_mfma_f32_16x16x32_bf16(
                        af[mi], bfr[ni], acc[mi][ni], 0, 0, 0);
        }
        __syncthreads();
    }

    // C/D layout (m89/m91): col = lane&15, row = (lane>>4)*4 + j
#pragma unroll
    for (int mi = 0; mi < 4; mi++)
#pragma unroll
        for (int ni = 0; ni < 4; ni++) {
            int gc = n0 + wc * 64 + ni * 16 + (lane & 15);
#pragma unroll
            for (int j = 0; j < 4; j++) {
                int gr = row0 + wr * 64 + mi * 16 + (lane >> 4) * 4 + j;
                if (gr < N) h1b[(size_t)gr * 256 + gc] = f2bf(acc[mi][ni][j]);
            }
        }
}

// as1/ad1 per (node, head) from bf16 h1. 32-lane group per node. [FROZEN]
__global__ __launch_bounds__(256) void alpha1_kernel(
        const ushort* __restrict__ h1b,
        const float* __restrict__ a_src1, const float* __restrict__ a_dst1,
        float* __restrict__ as1, float* __restrict__ ad1, int N) {
    int t = threadIdx.x;
    int g = t >> 5, l = t & 31;
    int node = blockIdx.x * 8 + g;
    if (node >= N) return;
    bf16x8 hv = *(const bf16x8*)&h1b[(size_t)node * 256 + l * 8];
    float s = 0.f, d = 0.f;
#pragma unroll
    for (int i = 0; i < 8; i++) {
        float h = bf2f((ushort)hv[i]);
        s = fmaf(h, a_src1[l * 8 + i], s);
        d = fmaf(h, a_dst1[l * 8 + i], d);
    }
    s += __shfl_xor(s, 1); s += __shfl_xor(s, 2);
    d += __shfl_xor(d, 1); d += __shfl_xor(d, 2);
    if ((l & 3) == 0) {
        as1[node * 8 + (l >> 2)] = s;
        ad1[node * 8 + (l >> 2)] = d;
    }
}

// Layer-1 FUSED softmax + gather (agg1f). [FROZEN from R13]
#define FMA8(W, V)                                                      \
    c0 = fmaf(W, bf2f((ushort)((V).x & 0xffffu)), c0);                  \
    c1 = fmaf(W, bf2f((ushort)((V).x >> 16)), c1);                      \
    c2 = fmaf(W, bf2f((ushort)((V).y & 0xffffu)), c2);                  \
    c3 = fmaf(W, bf2f((ushort)((V).y >> 16)), c3);                      \
    c4 = fmaf(W, bf2f((ushort)((V).z & 0xffffu)), c4);                  \
    c5 = fmaf(W, bf2f((ushort)((V).z >> 16)), c5);                      \
    c6 = fmaf(W, bf2f((ushort)((V).w & 0xffffu)), c6);                  \
    c7 = fmaf(W, bf2f((ushort)((V).w >> 16)), c7);

__global__ __launch_bounds__(256) void agg1f_kernel(
        const ushort* __restrict__ h1b,
        const float* __restrict__ as1, const float* __restrict__ ad1,
        const float* __restrict__ b1,
        const int* __restrict__ off, const int* __restrict__ esrc,
        ushort* __restrict__ hactb, int N) {
    __shared__ float s_w[8][32][8];     // 8 KB; [node-slot][edge][head]
    int t = threadIdx.x;
    int slot = t >> 5;                  // node slot 0..7 (2 per wave)
    int node = blockIdx.x * 8 + slot;
    int l = t & 31;                     // lane within half-wave
    if (node >= N) return;
    int beg = off[node], end = off[node + 1];
    int deg = end - beg;
    int h = l & 7, q = l >> 3;          // phase-1 role: edge-slot q (0..3), head h
    float adv = ad1[node * 8 + h];
    int head2 = l >> 2;                 // phase-2 role: 8 ch/lane, head = ch0/32
    int ch0 = l * 8;
    const ushort* hb = h1b + ch0;
    float c0 = 0.f, c1 = 0.f, c2 = 0.f, c3 = 0.f;
    float c4 = 0.f, c5 = 0.f, c6 = 0.f, c7 = 0.f;

    if (deg <= 32) {
        float e_r[8];
#pragma unroll
        for (int r = 0; r < 8; r++) {
            int j = beg + r * 4 + q;
            float e = -3.0e38f;
            if (j < end) {
                e = as1[esrc[j] * 8 + h] + adv;
                e = (e > 0.f) ? e : 0.2f * e;   // leaky_relu(0.2)
            }
            e_r[r] = e;
        }
        float m = e_r[0];
#pragma unroll
        for (int r = 1; r < 8; r++) m = fmaxf(m, e_r[r]);
        m = fmaxf(m, __shfl_xor(m, 8, 32));
        m = fmaxf(m, __shfl_xor(m, 16, 32));
        float dnm = 0.f;
#pragma unroll
        for (int r = 0; r < 8; r++)
            if (beg + r * 4 + q < end) dnm += __expf(e_r[r] - m);
        dnm += __shfl_xor(dnm, 8, 32);
        dnm += __shfl_xor(dnm, 16, 32);
        float inv = 1.f / (dnm + 1e-16f);
#pragma unroll
        for (int r = 0; r < 8; r++) {
            int j = beg + r * 4 + q;
            if (j < end) s_w[slot][r * 4 + q][h] = __expf(e_r[r] - m) * inv;
        }
        const float* wp = &s_w[slot][0][head2];
        int j = beg;
        for (; j + 4 <= end; j += 4) {
            int k = j - beg;
            int s0 = esrc[j + 0], s1 = esrc[j + 1], s2 = esrc[j + 2], s3 = esrc[j + 3];
            float w0 = wp[(k + 0) * 8];
            float w1 = wp[(k + 1) * 8];
            float w2 = wp[(k + 2) * 8];
            float w3 = wp[(k + 3) * 8];
            uint4 v0 = *(const uint4*)(hb + (size_t)s0 * 256);
            uint4 v1 = *(const uint4*)(hb + (size_t)s1 * 256);
            uint4 v2 = *(const uint4*)(hb + (size_t)s2 * 256);
            uint4 v3 = *(const uint4*)(hb + (size_t)s3 * 256);
            FMA8(w0, v0);
            FMA8(w1, v1);
            FMA8(w2, v2);
            FMA8(w3, v3);
        }
        for (; j < end; j++) {
            int s0 = esrc[j];
            float w = wp[(j - beg) * 8];
            uint4 v = *(const uint4*)(hb + (size_t)s0 * 256);
            FMA8(w, v);
        }
    } else {
        float m = -3.0e38f;
        for (int j0 = beg; j0 < end; j0 += 4) {
            int j = j0 + q;
            if (j < end) {
                float e = as1[esrc[j] * 8 + h] + adv;
                e = (e > 0.f) ? e : 0.2f * e;
                m = fmaxf(m, e);
            }
        }
        m = fmaxf(m, __shfl_xor(m, 8, 32));
        m = fmaxf(m, __shfl_xor(m, 16, 32));
        float dnm = 0.f;
        for (int j0 = beg; j0 < end; j0 += 4) {
            int j = j0 + q;
            if (j < end) {
                float e = as1[esrc[j] * 8 + h] + adv;
                e = (e > 0.f) ? e : 0.2f * e;
                dnm += __expf(e - m);
            }
        }
        dnm += __shfl_xor(dnm, 8, 32);
        dnm += __shfl_xor(dnm, 16, 32);
        float inv = 1.f / (dnm + 1e-16f);
        float m2   = __shfl(m, head2, 32);
        float inv2 = __shfl(inv, head2, 32);
        float adv2 = __shfl(adv, head2, 32);
        const float* asp = as1 + head2;
        for (int j = beg; j < end; j++) {
            int s0 = esrc[j];
            float e = asp[s0 * 8] + adv2;
            e = (e > 0.f) ? e : 0.2f * e;
            float w = __expf(e - m2) * inv2;
            uint4 v = *(const uint4*)(hb + (size_t)s0 * 256);
            FMA8(w, v);
        }
    }

    float4 bv0 = *(const float4*)&b1[ch0];
    float4 bv1 = *(const float4*)&b1[ch0 + 4];
    float o0 = c0 + bv0.x, o1 = c1 + bv0.y, o2 = c2 + bv0.z, o3 = c3 + bv0.w;
    float o4 = c4 + bv1.x, o5 = c5 + bv1.y, o6 = c6 + bv1.z, o7 = c7 + bv1.w;
    o0 = (o0 > 0.f) ? o0 : (__expf(o0) - 1.f);
    o1 = (o1 > 0.f) ? o1 : (__expf(o1) - 1.f);
    o2 = (o2 > 0.f) ? o2 : (__expf(o2) - 1.f);
    o3 = (o3 > 0.f) ? o3 : (__expf(o3) - 1.f);
    o4 = (o4 > 0.f) ? o4 : (__expf(o4) - 1.f);
    o5 = (o5 > 0.f) ? o5 : (__expf(o5) - 1.f);
    o6 = (o6 > 0.f) ? o6 : (__expf(o6) - 1.f);
    o7 = (o7 > 0.f) ? o7 : (__expf(o7) - 1.f);
    uint4 r;
    r.x = pack2(o0, o1);
    r.y = pack2(o2, o3);
    r.z = pack2(o4, o5);
    r.w = pack2(o6, o7);
    *(uint4*)(hactb + (size_t)node * 256 + ch0) = r;
}

// h2 = hactb @ W2 via bf16 MFMA. Tile 128x32, BK=64. [FROZEN]
__global__ __launch_bounds__(256) void gemm2_mfma(
        const ushort* __restrict__ hactb,  // [N][256] bf16
        const ushort* __restrict__ w2t,    // [32][256] bf16 (c-major)
        float* __restrict__ h2, int N) {
    __shared__ ushort Al[128 * LDA];
    __shared__ ushort Bl[32 * LDA];
    int t = threadIdx.x;
    int row0 = blockIdx.x * 128;
    int lane = t & 63, wid = t >> 6;

    f32x4 acc[2][2] = {};

    int sr = t >> 1, scs = (t & 1) * 32;
    for (int k0 = 0; k0 < 256; k0 += 64) {
        {
            int gr = row0 + sr;
            uint4 v0 = {0,0,0,0}, v1 = {0,0,0,0}, v2 = {0,0,0,0}, v3 = {0,0,0,0};
            if (gr < N) {
                const uint4* g = (const uint4*)(hactb + (size_t)gr * 256 + k0 + scs);
                v0 = g[0]; v1 = g[1]; v2 = g[2]; v3 = g[3];
            }
            uint4* d = (uint4*)&Al[sr * LDA + scs];
            d[0] = v0; d[1] = v1; d[2] = v2; d[3] = v3;
        }
        if (t < 64) {
            const uint4* g = (const uint4*)(w2t + (size_t)sr * 256 + k0 + scs);
            uint4* d = (uint4*)&Bl[sr * LDA + scs];
            d[0] = g[0]; d[1] = g[1]; d[2] = g[2]; d[3] = g[3];
        }
        __syncthreads();

#pragma unroll
        for (int ks = 0; ks < 2; ks++) {
            int kk = ks * 32 + (lane >> 4) * 8;
            bf16x8 af[2], bfr[2];
#pragma unroll
            for (int mi = 0; mi < 2; mi++) {
                int r = wid * 32 + mi * 16 + (lane & 15);
                af[mi] = *(const bf16x8*)&Al[r * LDA + kk];
            }
#pragma unroll
            for (int ni = 0; ni < 2; ni++) {
                int r = ni * 16 + (lane & 15);
                bfr[ni] = *(const bf16x8*)&Bl[r * LDA + kk];
            }
#pragma unroll
            for (int mi = 0; mi < 2; mi++)
#pragma unroll
                for (int ni = 0; ni < 2; ni++)
                    acc[mi][ni] = __builtin_amdgcn_mfma_f32_16x16x32_bf16(
                        af[mi], bfr[ni], acc[mi][ni], 0, 0, 0);
        }
        __syncthreads();
    }

#pragma unroll
    for (int mi = 0; mi < 2; mi++)
#pragma unroll
        for (int ni = 0; ni < 2; ni++) {
            int gc = ni * 16 + (lane & 15);
#pragma unroll
            for (int j = 0; j < 4; j++) {
                int gr = row0 + wid * 32 + mi * 16 + (lane >> 4) * 4 + j;
                if (gr < N) h2[(size_t)gr * 32 + gc] = acc[mi][ni][j];
            }
        }
}

// as2/ad2 from h2: 8-lane group per node, float4 loads. [FROZEN]
__global__ __launch_bounds__(256) void alpha2_kernel(
        const float* __restrict__ h2,
        const float* __restrict__ a_src2, const float* __restrict__ a_dst2,
        float* __restrict__ as2, float* __restrict__ ad2, int N) {
    int t = threadIdx.x;
    int g = t >> 3, q = t & 7;
    int node = blockIdx.x * 32 + g;
    if (node >= N) return;
    float4 v = *(const float4*)&h2[(size_t)node * 32 + q * 4];
    float4 sa = *(const float4*)&a_src2[q * 4];
    float4 da = *(const float4*)&a_dst2[q * 4];
    float s = v.x * sa.x + v.y * sa.y + v.z * sa.z + v.w * sa.w;
    float d = v.x * da.x + v.y * da.y + v.z * da.z + v.w * da.w;
    s += __shfl_xor(s, 1, 8); s += __shfl_xor(s, 2, 8); s += __shfl_xor(s, 4, 8);
    d += __shfl_xor(d, 1, 8); d += __shfl_xor(d, 2, 8); d += __shfl_xor(d, 4, 8);
    if (q == 0) { as2[node] = s; ad2[node] = d; }
}

// Layer-2 FUSED softmax + gather + bias + log_softmax (agg2f). [FROZEN R15]
__global__ __launch_bounds__(256) void agg2f_kernel(
        const float* __restrict__ h2,
        const float* __restrict__ as2, const float* __restrict__ ad2,
        const float* __restrict__ b2,
        const int* __restrict__ off, const int* __restrict__ esrc,
        float* __restrict__ out, int N) {
    __shared__ float s_w[8][32];        // 1 KB; [group][edge]
    int t = threadIdx.x;
    int g = t >> 5, c = t & 31;
    int node = blockIdx.x * 8 + g;
    if (node >= N) return;
    int beg = off[node], end = off[node + 1];
    int deg = end - beg;
    float adv = ad2[node];
    const float* hcol = h2 + c;
    float a0 = 0.f, a1 = 0.f, a2 = 0.f, a3 = 0.f;

    if (deg <= 32) {
        float e = -3.0e38f;
        if (c < deg) {
            float v = as2[esrc[beg + c]] + adv;
            e = (v > 0.f) ? v : 0.2f * v;   // leaky_relu(0.2)
        }
        float m = e;
#pragma unroll
        for (int s = 16; s > 0; s >>= 1) m = fmaxf(m, __shfl_xor(m, s, 32));
        float w = (c < deg) ? __expf(e - m) : 0.f;
        float dn = w;
#pragma unroll
        for (int s = 16; s > 0; s >>= 1) dn += __shfl_xor(dn, s, 32);
        s_w[g][c] = w * (1.f / (dn + 1e-16f));
        int j = beg;
        for (; j + 4 <= end; j += 4) {
            int k = j - beg;
            int s0 = esrc[j + 0], s1 = esrc[j + 1], s2 = esrc[j + 2], s3 = esrc[j + 3];
            float w0 = s_w[g][k + 0];
            float w1 = s_w[g][k + 1];
            float w2 = s_w[g][k + 2];
            float w3 = s_w[g][k + 3];
            a0 = fmaf(w0, hcol[(size_t)s0 * 32], a0);
            a1 = fmaf(w1, hcol[(size_t)s1 * 32], a1);
            a2 = fmaf(w2, hcol[(size_t)s2 * 32], a2);
            a3 = fmaf(w3, hcol[(size_t)s3 * 32], a3);
        }
        for (; j < end; j++)
            a0 = fmaf(s_w[g][j - beg], hcol[(size_t)esrc[j] * 32], a0);
    } else {
        float m = -3.0e38f, dnm = 0.f;
        for (int base = beg; base < end; base += 32) {
            int n_ch = min(32, end - base);
            float ej = -3.0e38f;
            if (c < n_ch) {
                float e = as2[esrc[base + c]] + adv;
                ej = (e > 0.f) ? e : 0.2f * e;
            }
            float cm = ej;
#pragma unroll
            for (int s = 16; s > 0; s >>= 1) cm = fmaxf(cm, __shfl_xor(cm, s, 32));
            float nm = fmaxf(m, cm);
            float scl = __expf(m - nm);
            float wj = (c < n_ch) ? __expf(ej - nm) : 0.f;
            float ws = wj;
#pragma unroll
            for (int s = 16; s > 0; s >>= 1) ws += __shfl_xor(ws, s, 32);
            dnm = dnm * scl + ws;
            m = nm;
        }
        float inv = 1.f / (dnm + 1e-16f);
        int j = beg;
        for (; j + 4 <= end; j += 4) {
            int s0 = esrc[j + 0], s1 = esrc[j + 1], s2 = esrc[j + 2], s3 = esrc[j + 3];
            float e0 = as2[s0] + adv, e1 = as2[s1] + adv;
            float e2 = as2[s2] + adv, e3 = as2[s3] + adv;
            e0 = (e0 > 0.f) ? e0 : 0.2f * e0;
            e1 = (e1 > 0.f) ? e1 : 0.2f * e1;
            e2 = (e2 > 0.f) ? e2 : 0.2f * e2;
            e3 = (e3 > 0.f) ? e3 : 0.2f * e3;
            float w0 = __expf(e0 - m) * inv, w1 = __expf(e1 - m) * inv;
            float w2 = __expf(e2 - m) * inv, w3 = __expf(e3 - m) * inv;
            a0 = fmaf(w0, hcol[(size_t)s0 * 32], a0);
            a1 = fmaf(w1, hcol[(size_t)s1 * 32], a1);
            a2 = fmaf(w2, hcol[(size_t)s2 * 32], a2);
            a3 = fmaf(w3, hcol[(size_t)s3 * 32], a3);
        }
        for (; j < end; j++) {
            int s0 = esrc[j];
            float e = as2[s0] + adv;
            e = (e > 0.f) ? e : 0.2f * e;
            a0 = fmaf(__expf(e - m) * inv, hcol[(size_t)s0 * 32], a0);
        }
    }

    float v = (a0 + a1) + (a2 + a3) + b2[c];
    float mx = v;
#pragma unroll
    for (int s = 16; s > 0; s >>= 1) mx = fmaxf(mx, __shfl_xor(mx, s, 32));
    float sum = __expf(v - mx);
#pragma unroll
    for (int s = 16; s > 0; s >>= 1) sum += __shfl_xor(sum, s, 32);
    out[(size_t)node * 32 + c] = (v - mx) - __logf(sum);
}

extern "C" void kernel_launch(void* const* d_in, const int* in_sizes, int n_in,
                              void* d_out, int out_size, void* d_ws, size_t ws_size,
                              hipStream_t stream) {
    const float* x      = (const float*)d_in[0];
    const void*  ei     = d_in[1];
    const float* W1     = (const float*)d_in[2];
    const float* a_src1 = (const float*)d_in[3];
    const float* a_dst1 = (const float*)d_in[4];
    const float* b1     = (const float*)d_in[5];
    const float* W2     = (const float*)d_in[6];
    const float* a_src2 = (const float*)d_in[7];
    const float* a_dst2 = (const float*)d_in[8];
    const float* b2     = (const float*)d_in[9];
    const int N  = in_sizes[0] / 256;   // 50000
    const int E  = in_sizes[1] / 2;     // 500000
    const int ET = E + N;
    float* outp = (float*)d_out;
    (void)n_in; (void)out_size; (void)ws_size;

    char* ws = (char*)d_ws;
    size_t o = 0;
    auto alloc = [&](size_t bytes) -> void* {
        void* p = ws + o;
        o += (bytes + 255) & ~(size_t)255;
        return p;
    };
    int*    src32  = (int*)alloc((size_t)ET * 4);
    int*    dst32  = (int*)alloc((size_t)ET * 4);
    int*    deg    = (int*)alloc((size_t)2 * N * 4);  // deg + cursor, one memset
    int*    cursor = deg + N;
    int*    off    = (int*)alloc((size_t)(N + 1) * 4);
    int*    esrc   = (int*)alloc((size_t)ET * 4);
    int*    bsum   = (int*)alloc((size_t)1024 * 4);
    ushort* w1t    = (ushort*)alloc((size_t)256 * 256 * 2);
    ushort* w2t    = (ushort*)alloc((size_t)32 * 256 * 2);
    ushort* h1b    = (ushort*)alloc((size_t)N * 256 * 2);
    float*  as1    = (float*)alloc((size_t)N * 8 * 4);
    float*  ad1    = (float*)alloc((size_t)N * 8 * 4);
    ushort* hactb  = (ushort*)alloc((size_t)N * 256 * 2);
    float*  h2     = (float*)alloc((size_t)N * 32 * 4);
    float*  as2    = (float*)alloc((size_t)N * 4);
    float*  ad2    = (float*)alloc((size_t)N * 4);

    const int nbScan = (N + 255) / 256;   // 196 (<= 256 required by scanC)

    hipMemsetAsync(deg, 0, (size_t)2 * N * 4, stream);
    decode_degree_kernel<<<(ET + 255) / 256, 256, 0, stream>>>(ei, E, ET, N,
                                                               src32, dst32, deg);
    scanA_kernel<<<nbScan, 256, 0, stream>>>(deg, bsum, N);
    scanC_kernel<<<nbScan, 256, 0, stream>>>(deg, bsum, off, N, nbScan);
    scatter_kernel<<<(ET + 255) / 256, 256, 0, stream>>>(src32, dst32, ET, off,
                                                         cursor, esrc);

    convert_w_kernel<<<96, 256, 0, stream>>>(W1, W2, w1t, w2t);

    gemm1_mfma<<<dim3((N + 127) / 128, 2), 256, 0, stream>>>(x, w1t, h1b, N);
    alpha1_kernel<<<(N + 7) / 8, 256, 0, stream>>>(h1b, a_src1, a_dst1, as1, ad1, N);
    agg1f_kernel<<<(N + 7) / 8, 256, 0, stream>>>(h1b, as1, ad1, b1, off, esrc,
                                                  hactb, N);
    gemm2_mfma<<<(N + 127) / 128, 256, 0, stream>>>(hactb, w2t, h2, N);
    alpha2_kernel<<<(N + 31) / 32, 256, 0, stream>>>(h2, a_src2, a_dst2, as2, ad2, N);
    agg2f_kernel<<<(N + 7) / 8, 256, 0, stream>>>(h2, as2, ad2, b2, off, esrc,
                                                  outp, N);
}